// Round 7
// baseline (2597.393 us; speedup 1.0000x reference)
//
#include <hip/hip_runtime.h>
#include <math.h>

#define FHh 100
#define FWw 160
#define CIN 512
#define COUT 512
#define NPIX 16000
#define NANCH 144000
#define PRE_NMS 6000
#define POST_NMS 300
#define EQCAP 8192

typedef double d4 __attribute__((ext_vector_type(4)));

// monotonic fp32 -> u32 key
__device__ __forceinline__ unsigned fkey(float x){
  unsigned b = __float_as_uint(x);
  return (b & 0x80000000u) ? ~b : (b | 0x80000000u);
}
// monotonic fp64 -> u64 key
__device__ __forceinline__ unsigned long long dkey(double x){
  unsigned long long u = (unsigned long long)__double_as_longlong(x);
  return (u & 0x8000000000000000ull) ? ~u : (u | 0x8000000000000000ull);
}
__device__ __forceinline__ unsigned long long shfl_u64(unsigned long long x, int lane){
  unsigned lo = (unsigned)x, hi = (unsigned)(x >> 32);
  lo = __shfl(lo, lane, 64);
  hi = __shfl(hi, lane, 64);
  return ((unsigned long long)hi << 32) | lo;
}

// ---------------- prep: head weights -> f64 transposed ----------------
__global__ __launch_bounds__(256) void prep_all(
    const float* __restrict__ Wc, const float* __restrict__ Wr,
    double* __restrict__ WcT, double* __restrict__ WrT)
{
  const int gid = blockIdx.x*256 + threadIdx.x;   // < 45*512 exactly (grid 90)
  const int n = gid >> 9, ci = gid & 511;
  if (n < 9) WcT[(size_t)n*512 + ci] = (double)Wc[ci*9 + n];
  else       WrT[(size_t)(n-9)*512 + ci] = (double)Wr[ci*36 + (n-9)];
}

// ---------------- 3x3 conv 512->512: A-in-LDS, B-from-L2 f64 MFMA GEMM ----------------
// 128px x 64co block tile, grid 1000 (co-major: cg*125 + tile, cg 0..7); 4 waves,
// each owning ONE feature row (32 px x 64 co, acc 2x4, 32 MFMAs/tap).
// A neighborhood (6x34 px, 16 k) in LDS once per kc (read-only across the 9 taps);
// B per-lane direct from f32 W1 (L1/L2-resident; all 4 waves share the 4KB tap slice).
// No per-tap barriers; 2 barriers per kc (Ns overwrite) = 64 total.
// __launch_bounds__(256,4) pins VGPR<=128 -> ~4 blocks/CU = ~4 waves/SIMD (2x r5's TLP).
// Per-output MFMA order (kc,tap,k4 ascending) unchanged -> bit-identical to r5.
// Fragment maps (r1/r2-verified):
//   A: lane holds A[row=l&15][k=l>>4];  B: lane holds B[k=l>>4][col=l&15]
//   D: lane l reg i -> C[row = 4*i + (l>>4)][col = l&15]
__global__ __launch_bounds__(256, 4) void conv_gemm(
    const float* __restrict__ fm, const float* __restrict__ W1,
    const float* __restrict__ b1, double* __restrict__ yd)
{
  __shared__ double Ns[16*204];        // A[k][nr*34+nc]  (26.1 KB)

  const int bid  = blockIdx.x;
  const int cg   = bid / 125;          // 0..7 co-group
  const int tile = bid - cg*125;       // 0..124
  const int rp   = tile / 5;           // 0..24
  const int xseg = tile - rp*5;        // 0..4
  const int x0   = xseg*32;
  const int row0 = rp*4;
  const int co0  = cg*64;

  const int tid  = threadIdx.x;
  const int lane = tid & 63;
  const int kl   = lane >> 4;
  const int cl   = lane & 15;
  const int wv   = tid >> 6;           // wave 0..3 -> feature row row0+wv, px base wv*32

  double pf[4][4];                     // A-prefetch regs (816 tasks / 256 thr = 4 iters)

  // ---- A prefetch: global f32 -> regs (f64), task t = px*4+kq, px = nr*34+nc ----
  auto APF_LOAD = [&](int kc){
    #pragma unroll
    for (int it = 0; it < 4; ++it){
      const int t  = it*256 + tid;
      const int px = t >> 2, kq = t & 3;
      const int nr = px / 34, nc = px - nr*34;
      const int row = row0 + nr - 1, col = x0 + nc - 1;
      const bool ok = (t < 816) && (row >= 0) && (row < FHh) && (col >= 0) && (col < FWw);
      if (ok){
        const float4 v = *(const float4*)(fm + ((size_t)(row*FWw + col))*CIN + kc*16 + kq*4);
        pf[it][0] = (double)v.x; pf[it][1] = (double)v.y;
        pf[it][2] = (double)v.z; pf[it][3] = (double)v.w;
      } else {
        pf[it][0] = pf[it][1] = pf[it][2] = pf[it][3] = 0.0;
      }
    }
  };
  auto APF_WRITE = [&](){
    #pragma unroll
    for (int it = 0; it < 4; ++it){
      const int t  = it*256 + tid;
      const int px = t >> 2, kq = t & 3;
      if (t < 816){
        #pragma unroll
        for (int u = 0; u < 4; ++u)
          Ns[(kq*4 + u)*204 + px] = pf[it][u];
      }
    }
  };

  d4 acc[2][4];
  #pragma unroll
  for (int mt = 0; mt < 2; ++mt)
    #pragma unroll
    for (int nt = 0; nt < 4; ++nt) acc[mt][nt] = (d4){0.0, 0.0, 0.0, 0.0};

  // prologue: stage A(kc0)
  APF_LOAD(0);
  APF_WRITE();
  __syncthreads();

  const int abase_t = kl*204 + cl;                    // per-thread A base in Ns
  const float* Bbase = W1 + (size_t)kl*512 + co0 + cl;   // + (tap*512+kc*16)*512

  #pragma unroll 1
  for (int kc = 0; kc < 32; ++kc){
    #pragma unroll 1
    for (int tap = 0; tap < 9; ++tap){
      if (tap == 7 && kc < 31) APF_LOAD(kc + 1);
      // ---- B fragment: 16 coalesced f32 loads from L1/L2 + exact cvt to f64 ----
      const float* Bt = Bbase + ((size_t)(tap*512 + kc*16))*512;
      double breg[16];
      #pragma unroll
      for (int k4 = 0; k4 < 4; ++k4)
        #pragma unroll
        for (int nt = 0; nt < 4; ++nt)
          breg[k4*4 + nt] = (double)Bt[k4*2048 + nt*16];
      // ---- A pointer for this tap (wave's feature row +dy, +dx halo) ----
      const int ty = tap / 3;
      const int dy = ty - 1, dx = (tap - ty*3) - 1;
      const double* An = Ns + abase_t + (wv + dy + 1)*34 + (dx + 1);
      __builtin_amdgcn_s_setprio(1);
      #pragma unroll
      for (int k4 = 0; k4 < 4; ++k4){
        const double a0 = An[k4*4*204 + 0];     // mt0: cols 0..15
        const double a1 = An[k4*4*204 + 16];    // mt1: cols 16..31
        const double b0 = breg[k4*4 + 0];
        const double b1v= breg[k4*4 + 1];
        const double b2 = breg[k4*4 + 2];
        const double b3 = breg[k4*4 + 3];
        acc[0][0] = __builtin_amdgcn_mfma_f64_16x16x4f64(a0, b0,  acc[0][0], 0, 0, 0);
        acc[0][1] = __builtin_amdgcn_mfma_f64_16x16x4f64(a0, b1v, acc[0][1], 0, 0, 0);
        acc[0][2] = __builtin_amdgcn_mfma_f64_16x16x4f64(a0, b2,  acc[0][2], 0, 0, 0);
        acc[0][3] = __builtin_amdgcn_mfma_f64_16x16x4f64(a0, b3,  acc[0][3], 0, 0, 0);
        acc[1][0] = __builtin_amdgcn_mfma_f64_16x16x4f64(a1, b0,  acc[1][0], 0, 0, 0);
        acc[1][1] = __builtin_amdgcn_mfma_f64_16x16x4f64(a1, b1v, acc[1][1], 0, 0, 0);
        acc[1][2] = __builtin_amdgcn_mfma_f64_16x16x4f64(a1, b2,  acc[1][2], 0, 0, 0);
        acc[1][3] = __builtin_amdgcn_mfma_f64_16x16x4f64(a1, b3,  acc[1][3], 0, 0, 0);
      }
      __builtin_amdgcn_s_setprio(0);
    }
    // kc boundary: all waves done reading Ns(kc) -> overwrite with kc+1
    __syncthreads();
    if (kc < 31){
      APF_WRITE();
      __syncthreads();
    }
  }
  // epilogue: bias + relu + store; D row = 4*reg + (lane>>4)
  double bb[4];
  #pragma unroll
  for (int nt = 0; nt < 4; ++nt) bb[nt] = (double)b1[co0 + nt*16 + cl];
  #pragma unroll
  for (int mt = 0; mt < 2; ++mt){
    #pragma unroll
    for (int i = 0; i < 4; ++i){
      const int rr = mt*16 + 4*i + kl;               // col within the feature row
      const int gpx = (row0 + wv)*FWw + x0 + rr;
      double* yrow = yd + (size_t)gpx*CIN + co0 + cl;
      #pragma unroll
      for (int nt = 0; nt < 4; ++nt){
        yrow[nt*16] = fmax(acc[mt][nt][i] + bb[nt], 0.0);
      }
    }
  }
}

// ---------------- 1x1 heads (f64): thread = one output n x 4 px ----------------
__global__ __launch_bounds__(256) void head2(
    const double* __restrict__ yd, const double* __restrict__ WcT, const float* __restrict__ bc,
    const double* __restrict__ WrT, const float* __restrict__ br,
    float* __restrict__ out, double* __restrict__ scored, double* __restrict__ regd)
{
  __shared__ double yl[8192];          // 16 px x 512
  const int bid = blockIdx.x, t = threadIdx.x;
  const double2* src = (const double2*)(yd + (size_t)bid * 8192);
  double2* dst = (double2*)yl;
  for (int j = t; j < 4096; j += 256) dst[j] = src[j];
  __syncthreads();
  if (t < 180){
    const int n  = t % 45;
    const int pq = t / 45;             // 0..3 -> px pq*4..pq*4+3
    const double* w = (n < 9) ? (WcT + (size_t)n*512) : (WrT + (size_t)(n-9)*512);
    const double* y0 = yl + (pq*4+0)*512;
    const double* y1 = yl + (pq*4+1)*512;
    const double* y2 = yl + (pq*4+2)*512;
    const double* y3 = yl + (pq*4+3)*512;
    double s0=0.0, s1=0.0, s2=0.0, s3=0.0;
    for (int ci = 0; ci < 512; ++ci){
      const double wv = w[ci];
      s0 = fma(y0[ci], wv, s0);
      s1 = fma(y1[ci], wv, s1);
      s2 = fma(y2[ci], wv, s2);
      s3 = fma(y3[ci], wv, s3);
    }
    const double sv[4] = {s0, s1, s2, s3};
    if (n < 9){
      const double bb = (double)bc[n];
      #pragma unroll
      for (int u = 0; u < 4; ++u){
        const double s = sv[u] + bb;
        const double sig = 1.0 / (1.0 + exp(-s));
        const int gi = (bid*16 + pq*4 + u)*9 + n;
        out[gi] = (float)sig;
        scored[gi] = sig;
      }
    } else {
      const int m = n - 9;
      const double bb = (double)br[m];
      #pragma unroll
      for (int u = 0; u < 4; ++u){
        const double s = sv[u] + bb;
        const int gi = (bid*16 + pq*4 + u)*36 + m;
        out[144000 + gi] = (float)s;
        regd[gi] = s;
      }
    }
  }
}

// ---------------- decode + clip + min-size (f64) + fused hi-histogram ----------------
__global__ __launch_bounds__(256) void decode_hist(
    const float* __restrict__ amap, const double* __restrict__ scored,
    const double* __restrict__ regd, double* __restrict__ boxesd,
    unsigned* __restrict__ key32, unsigned long long* __restrict__ nmskey,
    unsigned* __restrict__ hist)
{
  const int i = blockIdx.x*256 + threadIdx.x;
  if (i >= NANCH) return;
  const double a0=(double)amap[4*i+0], a1=(double)amap[4*i+1];
  const double a2=(double)amap[4*i+2], a3=(double)amap[4*i+3];
  const double d0=regd[4*i+0], d1=regd[4*i+1], d2=regd[4*i+2], d3=regd[4*i+3];
  const double ah = a2 - a0, aw = a3 - a1;
  const double cy = a0 + 0.5*ah + d0*ah;
  const double cx = a1 + 0.5*aw + d1*aw;
  const double h = ah * exp(d2), w = aw * exp(d3);
  double y1 = cy - 0.5*h, x1 = cx - 0.5*w, y2 = cy + 0.5*h, x2 = cx + 0.5*w;
  y1 = fmax(y1, 0.0); x1 = fmax(x1, 0.0);
  y2 = fmin(y2, 1600.0); x2 = fmin(x2, 2560.0);
  boxesd[4*i+0]=y1; boxesd[4*i+1]=x1; boxesd[4*i+2]=y2; boxesd[4*i+3]=x2;
  const double obj = scored[i];
  const bool ok = (y2 - y1 >= 16.0) && (x2 - x1 >= 16.0);
  const unsigned k32 = fkey((float)obj);
  key32[i] = k32;
  nmskey[i] = ok ? dkey(obj) : dkey(-1e9);
  atomicAdd(&hist[k32 >> 16], 1u);
}

// ---------------- top-6000 radix select on f32-rounded keys ----------------
__global__ __launch_bounds__(1024) void scan_hi(const unsigned* __restrict__ hist, int* __restrict__ meta){
  __shared__ unsigned part[1024];
  const int t = threadIdx.x;
  unsigned s = 0;
  for (int j = 0; j < 64; ++j) s += hist[65535 - (t*64 + j)];
  part[t] = s;
  __syncthreads();
  for (int off = 1; off < 1024; off <<= 1){
    unsigned v = (t >= off) ? part[t - off] : 0u;
    __syncthreads();
    part[t] += v;
    __syncthreads();
  }
  const unsigned incl = part[t], excl = incl - s;
  if (excl < PRE_NMS && incl >= PRE_NMS){
    unsigned cum = excl;
    for (int j = 0; j < 64; ++j){
      const int bin = 65535 - (t*64 + j);
      const unsigned c = hist[bin];
      if (cum + c >= PRE_NMS){ meta[0] = bin; meta[1] = (int)cum; break; }
      cum += c;
    }
  }
}

__global__ __launch_bounds__(256) void hist_lo(const unsigned* __restrict__ key,
                                               const int* __restrict__ meta, unsigned* __restrict__ hist){
  const int i = blockIdx.x*256 + threadIdx.x;
  if (i < NANCH){
    const unsigned k = key[i];
    if ((int)(k >> 16) == meta[0]) atomicAdd(&hist[k & 0xFFFFu], 1u);
  }
}

__global__ __launch_bounds__(1024) void scan_lo(const unsigned* __restrict__ hist, int* __restrict__ meta){
  __shared__ unsigned part[1024];
  const int t = threadIdx.x;
  const unsigned G0 = (unsigned)meta[1];
  unsigned s = 0;
  for (int j = 0; j < 64; ++j) s += hist[65535 - (t*64 + j)];
  part[t] = s;
  __syncthreads();
  for (int off = 1; off < 1024; off <<= 1){
    unsigned v = (t >= off) ? part[t - off] : 0u;
    __syncthreads();
    part[t] += v;
    __syncthreads();
  }
  const unsigned incl = G0 + part[t], excl = incl - s;
  if (excl < PRE_NMS && incl >= PRE_NMS){
    unsigned cum = excl;
    for (int j = 0; j < 64; ++j){
      const int bin = 65535 - (t*64 + j);
      const unsigned c = hist[bin];
      if (cum + c >= PRE_NMS){
        meta[2] = (int)(((unsigned)meta[0] << 16) | (unsigned)bin);
        meta[3] = (int)cum;
        meta[4] = PRE_NMS - (int)cum;
        break;
      }
      cum += c;
    }
  }
}

__global__ __launch_bounds__(256) void compact_k(
    const unsigned* __restrict__ key, const unsigned long long* __restrict__ nmskey,
    const double* __restrict__ boxesd, const int* __restrict__ meta,
    int* __restrict__ cnt, double* __restrict__ selboxd,
    unsigned long long* __restrict__ selkey, int* __restrict__ eqidx)
{
  const int i = blockIdx.x*256 + threadIdx.x;
  if (i >= NANCH) return;
  const unsigned k = key[i];
  const unsigned T = (unsigned)meta[2];
  if (k > T){
    const int s = atomicAdd(&cnt[0], 1);
    selboxd[4*s+0]=boxesd[4*i+0]; selboxd[4*s+1]=boxesd[4*i+1];
    selboxd[4*s+2]=boxesd[4*i+2]; selboxd[4*s+3]=boxesd[4*i+3];
    selkey[s] = nmskey[i];
  } else if (k == T){
    const int e = atomicAdd(&cnt[1], 1);
    if (e < EQCAP) eqidx[e] = i;
  }
}

__global__ __launch_bounds__(256) void rankeq(
    const double* __restrict__ scored, const double* __restrict__ boxesd,
    const unsigned long long* __restrict__ nmskey,
    const int* __restrict__ meta, const int* __restrict__ cnt,
    const int* __restrict__ eqidx, double* __restrict__ selboxd,
    unsigned long long* __restrict__ selkey)
{
  __shared__ int eq[EQCAP];
  const int t = threadIdx.x;
  int E = cnt[1]; if (E > EQCAP) E = EQCAP;
  const int R = meta[4], G2 = meta[3];
  for (int j = t; j < E; j += 256) eq[j] = eqidx[j];
  __syncthreads();
  for (int j = t; j < E; j += 256){
    const int my = eq[j];
    const double smy = scored[my];
    int rank = 0;
    for (int k2 = 0; k2 < E; ++k2){
      const int ok = eq[k2];
      const double sk = scored[ok];
      rank += ((sk > smy) || (sk == smy && ok < my)) ? 1 : 0;
    }
    if (rank < R){
      const int s = G2 + rank;
      selboxd[4*s+0]=boxesd[4*my+0]; selboxd[4*s+1]=boxesd[4*my+1];
      selboxd[4*s+2]=boxesd[4*my+2]; selboxd[4*s+3]=boxesd[4*my+3];
      selkey[s] = nmskey[my];
    }
  }
}

// ---------------- rank-by-counting scatter ----------------
__global__ __launch_bounds__(256) void rank_scatter(
    const unsigned long long* __restrict__ selkey, const double* __restrict__ selboxd,
    unsigned long long* __restrict__ skeys, double* __restrict__ sboxd)
{
  __shared__ unsigned long long k[PRE_NMS];
  const int t = threadIdx.x;
  for (int j = t; j < PRE_NMS; j += 256) k[j] = selkey[j];
  __syncthreads();
  const int j = blockIdx.x*256 + t;
  if (j >= PRE_NMS) return;
  const unsigned long long kj = k[j];
  int r = 0;
  for (int i = 0; i < PRE_NMS; i += 4){
    r += (int)((k[i+0] > kj) || (k[i+0] == kj && (i+0) < j));
    r += (int)((k[i+1] > kj) || (k[i+1] == kj && (i+1) < j));
    r += (int)((k[i+2] > kj) || (k[i+2] == kj && (i+2) < j));
    r += (int)((k[i+3] > kj) || (k[i+3] == kj && (i+3) < j));
  }
  skeys[r] = kj;
  sboxd[(size_t)r*4+0] = selboxd[(size_t)j*4+0];
  sboxd[(size_t)r*4+1] = selboxd[(size_t)j*4+1];
  sboxd[(size_t)r*4+2] = selboxd[(size_t)j*4+2];
  sboxd[(size_t)r*4+3] = selboxd[(size_t)j*4+3];
}

// ---------------- 6000x6000 IOU suppression bitmap ----------------
__global__ __launch_bounds__(256) void iou_bitmap(
    const double* __restrict__ sboxd, unsigned long long* __restrict__ rowbits)
{
  __shared__ double cbx[4096];           // 1024 col boxes
  const int g = blockIdx.y;              // 0..5 word-groups
  const int r0 = blockIdx.x * 16;
  const int t = threadIdx.x;
  const int cbase = g * 1024;
  for (int e = t; e < 4096; e += 256){
    const int bi = cbase + (e >> 2);
    cbx[e] = (bi < PRE_NMS) ? sboxd[(size_t)bi*4 + (e & 3)] : 0.0;
  }
  __syncthreads();
  const int r = r0 + (t >> 4);
  const int w = t & 15;
  const double by1 = sboxd[(size_t)r*4+0], bx1 = sboxd[(size_t)r*4+1];
  const double by2 = sboxd[(size_t)r*4+2], bx2 = sboxd[(size_t)r*4+3];
  const double a1 = fmax(by2-by1, 0.0) * fmax(bx2-bx1, 0.0);
  unsigned long long bits = 0ull;
  for (int b = 0; b < 64; ++b){
    const int bcol = (b + w) & 63;
    const int j = cbase + w*64 + bcol;
    if (j < PRE_NMS){
      const int ce = (w*64 + bcol)*4;
      const double c0 = cbx[ce+0], c1 = cbx[ce+1], c2 = cbx[ce+2], c3 = cbx[ce+3];
      const double yy1 = fmax(by1, c0), xx1 = fmax(bx1, c1);
      const double yy2 = fmin(by2, c2), xx2 = fmin(bx2, c3);
      const double inter = fmax(yy2-yy1, 0.0) * fmax(xx2-xx1, 0.0);
      const double a2 = fmax(c2-c0, 0.0) * fmax(c3-c1, 0.0);
      const double iou = inter / (a1 + a2 - inter + 1e-8);
      if (iou > 0.7) bits |= (1ull << bcol);
    }
  }
  rowbits[(size_t)r*128 + g*16 + w] = bits;
}

// ---------------- greedy scan with suppression bitmap ----------------
__global__ __launch_bounds__(64) void greedy(
    const unsigned long long* __restrict__ skeys, const double* __restrict__ sboxd,
    const unsigned long long* __restrict__ rowbits, float* __restrict__ outp)
{
  const int t = threadIdx.x;
  const unsigned long long KEYTH = dkey(-5.0e8);
  int bad = PRE_NMS;
  for (int j = t; j < PRE_NMS; j += 64){
    if (skeys[j] <= KEYTH){ bad = j; break; }
  }
  #pragma unroll
  for (int off = 32; off > 0; off >>= 1){
    const int o = __shfl_down(bad, off, 64);
    bad = (o < bad) ? o : bad;
  }
  const int ilim = __builtin_amdgcn_readfirstlane(bad);

  unsigned long long s0 = 0ull, s1 = 0ull;
  int emitted = 0;
  for (int i = 0; i < ilim && emitted < POST_NMS; ++i){
    const int w = i >> 6, b = i & 63;
    const unsigned long long w0 = shfl_u64(s0, w & 63);
    const unsigned long long w1 = shfl_u64(s1, (w - 64) & 63);
    const unsigned long long word = (w < 64) ? w0 : w1;
    if (!((word >> b) & 1ull)){
      if (t < 4) outp[4*emitted + t] = (float)sboxd[(size_t)i*4 + t];
      s0 |= rowbits[(size_t)i*128 + t];
      if (t < 30) s1 |= rowbits[(size_t)i*128 + 64 + t];
      ++emitted;
    }
  }
  for (int r = emitted; r < POST_NMS; ++r)
    if (t < 4) outp[4*r + t] = 0.f;
}

extern "C" void kernel_launch(void* const* d_in, const int* in_sizes, int n_in,
                              void* d_out, int out_size, void* d_ws, size_t ws_size,
                              hipStream_t stream)
{
  const float* fm   = (const float*)d_in[1];
  const float* amap = (const float*)d_in[2];
  const float* W1   = (const float*)d_in[4];
  const float* b1   = (const float*)d_in[5];
  const float* Wc   = (const float*)d_in[6];
  const float* bc   = (const float*)d_in[7];
  const float* Wr   = (const float*)d_in[8];
  const float* br   = (const float*)d_in[9];
  float* out = (float*)d_out;

  char* base = (char*)d_ws;
  size_t off = 0;
  auto A = [&](size_t n) -> char* {
    char* p = base + off;
    off = (off + n + 255) & ~(size_t)255;
    return p;
  };
  double* yd      = (double*)A(65536000);
  double* WcT     = (double*)A(36864);
  double* WrT     = (double*)A(147456);
  double* scored  = (double*)A(1152000);
  double* regd    = (double*)A(4608000);
  unsigned* histc = (unsigned*)A(524328);        // hist1|hist2|cnt|meta contiguous
  double* boxesd              = (double*)A(4608000);
  unsigned long long* nmskey  = (unsigned long long*)A(1152000);
  unsigned* key32             = (unsigned*)A(576000);
  double* selboxd             = (double*)A(192000);
  unsigned long long* selkey  = (unsigned long long*)A(48000);
  unsigned long long* skeys   = (unsigned long long*)A(48000);
  double* sboxd               = (double*)A(192000);
  unsigned long long* rowbits = (unsigned long long*)A(6144000);
  int* eqidx                  = (int*)A(32768);

  unsigned* hist1 = histc;
  unsigned* hist2 = histc + 65536;
  int* cnt        = (int*)(histc + 131072);
  int* meta       = cnt + 2;

  hipMemsetAsync(histc, 0, (size_t)524328, stream);

  hipLaunchKernelGGL(prep_all, dim3(90), dim3(256), 0, stream,
                     Wc, Wr, WcT, WrT);
  hipLaunchKernelGGL(conv_gemm, dim3(1000), dim3(256), 0, stream, fm, W1, b1, yd);
  hipLaunchKernelGGL(head2, dim3(1000), dim3(256), 0, stream, yd, WcT, bc, WrT, br, out, scored, regd);
  hipLaunchKernelGGL(decode_hist, dim3((NANCH + 255)/256), dim3(256), 0, stream,
                     amap, scored, regd, boxesd, key32, nmskey, hist1);
  hipLaunchKernelGGL(scan_hi, dim3(1), dim3(1024), 0, stream, hist1, meta);
  hipLaunchKernelGGL(hist_lo, dim3((NANCH + 255)/256), dim3(256), 0, stream, key32, meta, hist2);
  hipLaunchKernelGGL(scan_lo, dim3(1), dim3(1024), 0, stream, hist2, meta);
  hipLaunchKernelGGL(compact_k, dim3((NANCH + 255)/256), dim3(256), 0, stream,
                     key32, nmskey, boxesd, meta, cnt, selboxd, selkey, eqidx);
  hipLaunchKernelGGL(rankeq, dim3(1), dim3(256), 0, stream,
                     scored, boxesd, nmskey, meta, cnt, eqidx, selboxd, selkey);
  hipLaunchKernelGGL(rank_scatter, dim3((PRE_NMS + 255)/256), dim3(256), 0, stream,
                     selkey, selboxd, skeys, sboxd);
  hipLaunchKernelGGL(iou_bitmap, dim3(375, 6), dim3(256), 0, stream, sboxd, rowbits);
  hipLaunchKernelGGL(greedy, dim3(1), dim3(64), 0, stream, skeys, sboxd, rowbits, out + 720000);
}

// Round 8
// 2149.938 us; speedup vs baseline: 1.2081x; 1.2081x over previous
//
#include <hip/hip_runtime.h>
#include <math.h>

#define FHh 100
#define FWw 160
#define CIN 512
#define COUT 512
#define NPIX 16000
#define NANCH 144000
#define PRE_NMS 6000
#define POST_NMS 300
#define EQCAP 8192

typedef double d4 __attribute__((ext_vector_type(4)));

// monotonic fp32 -> u32 key
__device__ __forceinline__ unsigned fkey(float x){
  unsigned b = __float_as_uint(x);
  return (b & 0x80000000u) ? ~b : (b | 0x80000000u);
}
// monotonic fp64 -> u64 key
__device__ __forceinline__ unsigned long long dkey(double x){
  unsigned long long u = (unsigned long long)__double_as_longlong(x);
  return (u & 0x8000000000000000ull) ? ~u : (u | 0x8000000000000000ull);
}
__device__ __forceinline__ unsigned long long shfl_u64(unsigned long long x, int lane){
  unsigned lo = (unsigned)x, hi = (unsigned)(x >> 32);
  lo = __shfl(lo, lane, 64);
  hi = __shfl(hi, lane, 64);
  return ((unsigned long long)hi << 32) | lo;
}

// ---------------- prep: head weights -> f64 transposed ----------------
__global__ __launch_bounds__(256) void prep_all(
    const float* __restrict__ Wc, const float* __restrict__ Wr,
    double* __restrict__ WcT, double* __restrict__ WrT)
{
  const int gid = blockIdx.x*256 + threadIdx.x;   // < 45*512 exactly (grid 90)
  const int n = gid >> 9, ci = gid & 511;
  if (n < 9) WcT[(size_t)n*512 + ci] = (double)Wc[ci*9 + n];
  else       WrT[(size_t)(n-9)*512 + ci] = (double)Wr[ci*36 + (n-9)];
}

// ---------------- 3x3 conv 512->512: A-in-LDS, B-from-L2 f64 MFMA GEMM ----------------
// 128px x 64co block tile, grid 1000 (co-major: cg*125 + tile, cg 0..7); 4 waves,
// each owning ONE feature row (32 px x 64 co, acc 2x4, 32 MFMAs/tap).
// A neighborhood (6x34 px, 16 k) in LDS once per kc (read-only across the 9 taps);
// B per-lane direct from f32 W1 (L1/L2-resident; all 4 waves share the 4KB tap slice).
// No per-tap barriers; 2 barriers per kc (Ns overwrite) = 64 total.
// r6 lesson: (256,4) forced VGPR=64 -> scratch spills (WRITE 64MB->721MB, MfmaUtil 55%).
// (256,3) caps ~170 VGPR: no spill; 3-4 blocks/CU = 1.5-2x r5's TLP.
// Per-output MFMA order (kc,tap,k4 ascending) unchanged -> bit-identical to r5/r6.
// Fragment maps (r1/r2-verified):
//   A: lane holds A[row=l&15][k=l>>4];  B: lane holds B[k=l>>4][col=l&15]
//   D: lane l reg i -> C[row = 4*i + (l>>4)][col = l&15]
__global__ __launch_bounds__(256, 3) void conv_gemm(
    const float* __restrict__ fm, const float* __restrict__ W1,
    const float* __restrict__ b1, double* __restrict__ yd)
{
  __shared__ double Ns[16*204];        // A[k][nr*34+nc]  (26.1 KB)

  const int bid  = blockIdx.x;
  const int cg   = bid / 125;          // 0..7 co-group
  const int tile = bid - cg*125;       // 0..124
  const int rp   = tile / 5;           // 0..24
  const int xseg = tile - rp*5;        // 0..4
  const int x0   = xseg*32;
  const int row0 = rp*4;
  const int co0  = cg*64;

  const int tid  = threadIdx.x;
  const int lane = tid & 63;
  const int kl   = lane >> 4;
  const int cl   = lane & 15;
  const int wv   = tid >> 6;           // wave 0..3 -> feature row row0+wv, px base wv*32

  double pf[4][4];                     // A-prefetch regs (816 tasks / 256 thr = 4 iters)

  // ---- A prefetch: global f32 -> regs (f64), task t = px*4+kq, px = nr*34+nc ----
  auto APF_LOAD = [&](int kc){
    #pragma unroll
    for (int it = 0; it < 4; ++it){
      const int t  = it*256 + tid;
      const int px = t >> 2, kq = t & 3;
      const int nr = px / 34, nc = px - nr*34;
      const int row = row0 + nr - 1, col = x0 + nc - 1;
      const bool ok = (t < 816) && (row >= 0) && (row < FHh) && (col >= 0) && (col < FWw);
      if (ok){
        const float4 v = *(const float4*)(fm + ((size_t)(row*FWw + col))*CIN + kc*16 + kq*4);
        pf[it][0] = (double)v.x; pf[it][1] = (double)v.y;
        pf[it][2] = (double)v.z; pf[it][3] = (double)v.w;
      } else {
        pf[it][0] = pf[it][1] = pf[it][2] = pf[it][3] = 0.0;
      }
    }
  };
  auto APF_WRITE = [&](){
    #pragma unroll
    for (int it = 0; it < 4; ++it){
      const int t  = it*256 + tid;
      const int px = t >> 2, kq = t & 3;
      if (t < 816){
        #pragma unroll
        for (int u = 0; u < 4; ++u)
          Ns[(kq*4 + u)*204 + px] = pf[it][u];
      }
    }
  };

  d4 acc[2][4];
  #pragma unroll
  for (int mt = 0; mt < 2; ++mt)
    #pragma unroll
    for (int nt = 0; nt < 4; ++nt) acc[mt][nt] = (d4){0.0, 0.0, 0.0, 0.0};

  // prologue: stage A(kc0)
  APF_LOAD(0);
  APF_WRITE();
  __syncthreads();

  const int abase_t = kl*204 + cl;                    // per-thread A base in Ns
  const float* Bbase = W1 + (size_t)kl*512 + co0 + cl;   // + (tap*512+kc*16)*512

  #pragma unroll 1
  for (int kc = 0; kc < 32; ++kc){
    #pragma unroll 1
    for (int tap = 0; tap < 9; ++tap){
      if (tap == 7 && kc < 31) APF_LOAD(kc + 1);
      // ---- B fragment: 16 coalesced f32 loads from L1/L2 + exact cvt to f64 ----
      const float* Bt = Bbase + ((size_t)(tap*512 + kc*16))*512;
      double breg[16];
      #pragma unroll
      for (int k4 = 0; k4 < 4; ++k4)
        #pragma unroll
        for (int nt = 0; nt < 4; ++nt)
          breg[k4*4 + nt] = (double)Bt[k4*2048 + nt*16];
      // ---- A pointer for this tap (wave's feature row +dy, +dx halo) ----
      const int ty = tap / 3;
      const int dy = ty - 1, dx = (tap - ty*3) - 1;
      const double* An = Ns + abase_t + (wv + dy + 1)*34 + (dx + 1);
      __builtin_amdgcn_s_setprio(1);
      #pragma unroll
      for (int k4 = 0; k4 < 4; ++k4){
        const double a0 = An[k4*4*204 + 0];     // mt0: cols 0..15
        const double a1 = An[k4*4*204 + 16];    // mt1: cols 16..31
        const double b0 = breg[k4*4 + 0];
        const double b1v= breg[k4*4 + 1];
        const double b2 = breg[k4*4 + 2];
        const double b3 = breg[k4*4 + 3];
        acc[0][0] = __builtin_amdgcn_mfma_f64_16x16x4f64(a0, b0,  acc[0][0], 0, 0, 0);
        acc[0][1] = __builtin_amdgcn_mfma_f64_16x16x4f64(a0, b1v, acc[0][1], 0, 0, 0);
        acc[0][2] = __builtin_amdgcn_mfma_f64_16x16x4f64(a0, b2,  acc[0][2], 0, 0, 0);
        acc[0][3] = __builtin_amdgcn_mfma_f64_16x16x4f64(a0, b3,  acc[0][3], 0, 0, 0);
        acc[1][0] = __builtin_amdgcn_mfma_f64_16x16x4f64(a1, b0,  acc[1][0], 0, 0, 0);
        acc[1][1] = __builtin_amdgcn_mfma_f64_16x16x4f64(a1, b1v, acc[1][1], 0, 0, 0);
        acc[1][2] = __builtin_amdgcn_mfma_f64_16x16x4f64(a1, b2,  acc[1][2], 0, 0, 0);
        acc[1][3] = __builtin_amdgcn_mfma_f64_16x16x4f64(a1, b3,  acc[1][3], 0, 0, 0);
      }
      __builtin_amdgcn_s_setprio(0);
    }
    // kc boundary: all waves done reading Ns(kc) -> overwrite with kc+1
    __syncthreads();
    if (kc < 31){
      APF_WRITE();
      __syncthreads();
    }
  }
  // epilogue: bias + relu + store; D row = 4*reg + (lane>>4)
  double bb[4];
  #pragma unroll
  for (int nt = 0; nt < 4; ++nt) bb[nt] = (double)b1[co0 + nt*16 + cl];
  #pragma unroll
  for (int mt = 0; mt < 2; ++mt){
    #pragma unroll
    for (int i = 0; i < 4; ++i){
      const int rr = mt*16 + 4*i + kl;               // col within the feature row
      const int gpx = (row0 + wv)*FWw + x0 + rr;
      double* yrow = yd + (size_t)gpx*CIN + co0 + cl;
      #pragma unroll
      for (int nt = 0; nt < 4; ++nt){
        yrow[nt*16] = fmax(acc[mt][nt][i] + bb[nt], 0.0);
      }
    }
  }
}

// ---------------- 1x1 heads (f64): thread = one output n x 4 px ----------------
__global__ __launch_bounds__(256) void head2(
    const double* __restrict__ yd, const double* __restrict__ WcT, const float* __restrict__ bc,
    const double* __restrict__ WrT, const float* __restrict__ br,
    float* __restrict__ out, double* __restrict__ scored, double* __restrict__ regd)
{
  __shared__ double yl[8192];          // 16 px x 512
  const int bid = blockIdx.x, t = threadIdx.x;
  const double2* src = (const double2*)(yd + (size_t)bid * 8192);
  double2* dst = (double2*)yl;
  for (int j = t; j < 4096; j += 256) dst[j] = src[j];
  __syncthreads();
  if (t < 180){
    const int n  = t % 45;
    const int pq = t / 45;             // 0..3 -> px pq*4..pq*4+3
    const double* w = (n < 9) ? (WcT + (size_t)n*512) : (WrT + (size_t)(n-9)*512);
    const double* y0 = yl + (pq*4+0)*512;
    const double* y1 = yl + (pq*4+1)*512;
    const double* y2 = yl + (pq*4+2)*512;
    const double* y3 = yl + (pq*4+3)*512;
    double s0=0.0, s1=0.0, s2=0.0, s3=0.0;
    for (int ci = 0; ci < 512; ++ci){
      const double wv = w[ci];
      s0 = fma(y0[ci], wv, s0);
      s1 = fma(y1[ci], wv, s1);
      s2 = fma(y2[ci], wv, s2);
      s3 = fma(y3[ci], wv, s3);
    }
    const double sv[4] = {s0, s1, s2, s3};
    if (n < 9){
      const double bb = (double)bc[n];
      #pragma unroll
      for (int u = 0; u < 4; ++u){
        const double s = sv[u] + bb;
        const double sig = 1.0 / (1.0 + exp(-s));
        const int gi = (bid*16 + pq*4 + u)*9 + n;
        out[gi] = (float)sig;
        scored[gi] = sig;
      }
    } else {
      const int m = n - 9;
      const double bb = (double)br[m];
      #pragma unroll
      for (int u = 0; u < 4; ++u){
        const double s = sv[u] + bb;
        const int gi = (bid*16 + pq*4 + u)*36 + m;
        out[144000 + gi] = (float)s;
        regd[gi] = s;
      }
    }
  }
}

// ---------------- decode + clip + min-size (f64) + fused hi-histogram ----------------
__global__ __launch_bounds__(256) void decode_hist(
    const float* __restrict__ amap, const double* __restrict__ scored,
    const double* __restrict__ regd, double* __restrict__ boxesd,
    unsigned* __restrict__ key32, unsigned long long* __restrict__ nmskey,
    unsigned* __restrict__ hist)
{
  const int i = blockIdx.x*256 + threadIdx.x;
  if (i >= NANCH) return;
  const double a0=(double)amap[4*i+0], a1=(double)amap[4*i+1];
  const double a2=(double)amap[4*i+2], a3=(double)amap[4*i+3];
  const double d0=regd[4*i+0], d1=regd[4*i+1], d2=regd[4*i+2], d3=regd[4*i+3];
  const double ah = a2 - a0, aw = a3 - a1;
  const double cy = a0 + 0.5*ah + d0*ah;
  const double cx = a1 + 0.5*aw + d1*aw;
  const double h = ah * exp(d2), w = aw * exp(d3);
  double y1 = cy - 0.5*h, x1 = cx - 0.5*w, y2 = cy + 0.5*h, x2 = cx + 0.5*w;
  y1 = fmax(y1, 0.0); x1 = fmax(x1, 0.0);
  y2 = fmin(y2, 1600.0); x2 = fmin(x2, 2560.0);
  boxesd[4*i+0]=y1; boxesd[4*i+1]=x1; boxesd[4*i+2]=y2; boxesd[4*i+3]=x2;
  const double obj = scored[i];
  const bool ok = (y2 - y1 >= 16.0) && (x2 - x1 >= 16.0);
  const unsigned k32 = fkey((float)obj);
  key32[i] = k32;
  nmskey[i] = ok ? dkey(obj) : dkey(-1e9);
  atomicAdd(&hist[k32 >> 16], 1u);
}

// ---------------- top-6000 radix select on f32-rounded keys ----------------
__global__ __launch_bounds__(1024) void scan_hi(const unsigned* __restrict__ hist, int* __restrict__ meta){
  __shared__ unsigned part[1024];
  const int t = threadIdx.x;
  unsigned s = 0;
  for (int j = 0; j < 64; ++j) s += hist[65535 - (t*64 + j)];
  part[t] = s;
  __syncthreads();
  for (int off = 1; off < 1024; off <<= 1){
    unsigned v = (t >= off) ? part[t - off] : 0u;
    __syncthreads();
    part[t] += v;
    __syncthreads();
  }
  const unsigned incl = part[t], excl = incl - s;
  if (excl < PRE_NMS && incl >= PRE_NMS){
    unsigned cum = excl;
    for (int j = 0; j < 64; ++j){
      const int bin = 65535 - (t*64 + j);
      const unsigned c = hist[bin];
      if (cum + c >= PRE_NMS){ meta[0] = bin; meta[1] = (int)cum; break; }
      cum += c;
    }
  }
}

__global__ __launch_bounds__(256) void hist_lo(const unsigned* __restrict__ key,
                                               const int* __restrict__ meta, unsigned* __restrict__ hist){
  const int i = blockIdx.x*256 + threadIdx.x;
  if (i < NANCH){
    const unsigned k = key[i];
    if ((int)(k >> 16) == meta[0]) atomicAdd(&hist[k & 0xFFFFu], 1u);
  }
}

__global__ __launch_bounds__(1024) void scan_lo(const unsigned* __restrict__ hist, int* __restrict__ meta){
  __shared__ unsigned part[1024];
  const int t = threadIdx.x;
  const unsigned G0 = (unsigned)meta[1];
  unsigned s = 0;
  for (int j = 0; j < 64; ++j) s += hist[65535 - (t*64 + j)];
  part[t] = s;
  __syncthreads();
  for (int off = 1; off < 1024; off <<= 1){
    unsigned v = (t >= off) ? part[t - off] : 0u;
    __syncthreads();
    part[t] += v;
    __syncthreads();
  }
  const unsigned incl = G0 + part[t], excl = incl - s;
  if (excl < PRE_NMS && incl >= PRE_NMS){
    unsigned cum = excl;
    for (int j = 0; j < 64; ++j){
      const int bin = 65535 - (t*64 + j);
      const unsigned c = hist[bin];
      if (cum + c >= PRE_NMS){
        meta[2] = (int)(((unsigned)meta[0] << 16) | (unsigned)bin);
        meta[3] = (int)cum;
        meta[4] = PRE_NMS - (int)cum;
        break;
      }
      cum += c;
    }
  }
}

__global__ __launch_bounds__(256) void compact_k(
    const unsigned* __restrict__ key, const unsigned long long* __restrict__ nmskey,
    const double* __restrict__ boxesd, const int* __restrict__ meta,
    int* __restrict__ cnt, double* __restrict__ selboxd,
    unsigned long long* __restrict__ selkey, int* __restrict__ eqidx)
{
  const int i = blockIdx.x*256 + threadIdx.x;
  if (i >= NANCH) return;
  const unsigned k = key[i];
  const unsigned T = (unsigned)meta[2];
  if (k > T){
    const int s = atomicAdd(&cnt[0], 1);
    selboxd[4*s+0]=boxesd[4*i+0]; selboxd[4*s+1]=boxesd[4*i+1];
    selboxd[4*s+2]=boxesd[4*i+2]; selboxd[4*s+3]=boxesd[4*i+3];
    selkey[s] = nmskey[i];
  } else if (k == T){
    const int e = atomicAdd(&cnt[1], 1);
    if (e < EQCAP) eqidx[e] = i;
  }
}

__global__ __launch_bounds__(256) void rankeq(
    const double* __restrict__ scored, const double* __restrict__ boxesd,
    const unsigned long long* __restrict__ nmskey,
    const int* __restrict__ meta, const int* __restrict__ cnt,
    const int* __restrict__ eqidx, double* __restrict__ selboxd,
    unsigned long long* __restrict__ selkey)
{
  __shared__ int eq[EQCAP];
  const int t = threadIdx.x;
  int E = cnt[1]; if (E > EQCAP) E = EQCAP;
  const int R = meta[4], G2 = meta[3];
  for (int j = t; j < E; j += 256) eq[j] = eqidx[j];
  __syncthreads();
  for (int j = t; j < E; j += 256){
    const int my = eq[j];
    const double smy = scored[my];
    int rank = 0;
    for (int k2 = 0; k2 < E; ++k2){
      const int ok = eq[k2];
      const double sk = scored[ok];
      rank += ((sk > smy) || (sk == smy && ok < my)) ? 1 : 0;
    }
    if (rank < R){
      const int s = G2 + rank;
      selboxd[4*s+0]=boxesd[4*my+0]; selboxd[4*s+1]=boxesd[4*my+1];
      selboxd[4*s+2]=boxesd[4*my+2]; selboxd[4*s+3]=boxesd[4*my+3];
      selkey[s] = nmskey[my];
    }
  }
}

// ---------------- rank-by-counting scatter ----------------
__global__ __launch_bounds__(256) void rank_scatter(
    const unsigned long long* __restrict__ selkey, const double* __restrict__ selboxd,
    unsigned long long* __restrict__ skeys, double* __restrict__ sboxd)
{
  __shared__ unsigned long long k[PRE_NMS];
  const int t = threadIdx.x;
  for (int j = t; j < PRE_NMS; j += 256) k[j] = selkey[j];
  __syncthreads();
  const int j = blockIdx.x*256 + t;
  if (j >= PRE_NMS) return;
  const unsigned long long kj = k[j];
  int r = 0;
  for (int i = 0; i < PRE_NMS; i += 4){
    r += (int)((k[i+0] > kj) || (k[i+0] == kj && (i+0) < j));
    r += (int)((k[i+1] > kj) || (k[i+1] == kj && (i+1) < j));
    r += (int)((k[i+2] > kj) || (k[i+2] == kj && (i+2) < j));
    r += (int)((k[i+3] > kj) || (k[i+3] == kj && (i+3) < j));
  }
  skeys[r] = kj;
  sboxd[(size_t)r*4+0] = selboxd[(size_t)j*4+0];
  sboxd[(size_t)r*4+1] = selboxd[(size_t)j*4+1];
  sboxd[(size_t)r*4+2] = selboxd[(size_t)j*4+2];
  sboxd[(size_t)r*4+3] = selboxd[(size_t)j*4+3];
}

// ---------------- 6000x6000 IOU suppression bitmap ----------------
__global__ __launch_bounds__(256) void iou_bitmap(
    const double* __restrict__ sboxd, unsigned long long* __restrict__ rowbits)
{
  __shared__ double cbx[4096];           // 1024 col boxes
  const int g = blockIdx.y;              // 0..5 word-groups
  const int r0 = blockIdx.x * 16;
  const int t = threadIdx.x;
  const int cbase = g * 1024;
  for (int e = t; e < 4096; e += 256){
    const int bi = cbase + (e >> 2);
    cbx[e] = (bi < PRE_NMS) ? sboxd[(size_t)bi*4 + (e & 3)] : 0.0;
  }
  __syncthreads();
  const int r = r0 + (t >> 4);
  const int w = t & 15;
  const double by1 = sboxd[(size_t)r*4+0], bx1 = sboxd[(size_t)r*4+1];
  const double by2 = sboxd[(size_t)r*4+2], bx2 = sboxd[(size_t)r*4+3];
  const double a1 = fmax(by2-by1, 0.0) * fmax(bx2-bx1, 0.0);
  unsigned long long bits = 0ull;
  for (int b = 0; b < 64; ++b){
    const int bcol = (b + w) & 63;
    const int j = cbase + w*64 + bcol;
    if (j < PRE_NMS){
      const int ce = (w*64 + bcol)*4;
      const double c0 = cbx[ce+0], c1 = cbx[ce+1], c2 = cbx[ce+2], c3 = cbx[ce+3];
      const double yy1 = fmax(by1, c0), xx1 = fmax(bx1, c1);
      const double yy2 = fmin(by2, c2), xx2 = fmin(bx2, c3);
      const double inter = fmax(yy2-yy1, 0.0) * fmax(xx2-xx1, 0.0);
      const double a2 = fmax(c2-c0, 0.0) * fmax(c3-c1, 0.0);
      const double iou = inter / (a1 + a2 - inter + 1e-8);
      if (iou > 0.7) bits |= (1ull << bcol);
    }
  }
  rowbits[(size_t)r*128 + g*16 + w] = bits;
}

// ---------------- greedy scan with suppression bitmap ----------------
__global__ __launch_bounds__(64) void greedy(
    const unsigned long long* __restrict__ skeys, const double* __restrict__ sboxd,
    const unsigned long long* __restrict__ rowbits, float* __restrict__ outp)
{
  const int t = threadIdx.x;
  const unsigned long long KEYTH = dkey(-5.0e8);
  int bad = PRE_NMS;
  for (int j = t; j < PRE_NMS; j += 64){
    if (skeys[j] <= KEYTH){ bad = j; break; }
  }
  #pragma unroll
  for (int off = 32; off > 0; off >>= 1){
    const int o = __shfl_down(bad, off, 64);
    bad = (o < bad) ? o : bad;
  }
  const int ilim = __builtin_amdgcn_readfirstlane(bad);

  unsigned long long s0 = 0ull, s1 = 0ull;
  int emitted = 0;
  for (int i = 0; i < ilim && emitted < POST_NMS; ++i){
    const int w = i >> 6, b = i & 63;
    const unsigned long long w0 = shfl_u64(s0, w & 63);
    const unsigned long long w1 = shfl_u64(s1, (w - 64) & 63);
    const unsigned long long word = (w < 64) ? w0 : w1;
    if (!((word >> b) & 1ull)){
      if (t < 4) outp[4*emitted + t] = (float)sboxd[(size_t)i*4 + t];
      s0 |= rowbits[(size_t)i*128 + t];
      if (t < 30) s1 |= rowbits[(size_t)i*128 + 64 + t];
      ++emitted;
    }
  }
  for (int r = emitted; r < POST_NMS; ++r)
    if (t < 4) outp[4*r + t] = 0.f;
}

extern "C" void kernel_launch(void* const* d_in, const int* in_sizes, int n_in,
                              void* d_out, int out_size, void* d_ws, size_t ws_size,
                              hipStream_t stream)
{
  const float* fm   = (const float*)d_in[1];
  const float* amap = (const float*)d_in[2];
  const float* W1   = (const float*)d_in[4];
  const float* b1   = (const float*)d_in[5];
  const float* Wc   = (const float*)d_in[6];
  const float* bc   = (const float*)d_in[7];
  const float* Wr   = (const float*)d_in[8];
  const float* br   = (const float*)d_in[9];
  float* out = (float*)d_out;

  char* base = (char*)d_ws;
  size_t off = 0;
  auto A = [&](size_t n) -> char* {
    char* p = base + off;
    off = (off + n + 255) & ~(size_t)255;
    return p;
  };
  double* yd      = (double*)A(65536000);
  double* WcT     = (double*)A(36864);
  double* WrT     = (double*)A(147456);
  double* scored  = (double*)A(1152000);
  double* regd    = (double*)A(4608000);
  unsigned* histc = (unsigned*)A(524328);        // hist1|hist2|cnt|meta contiguous
  double* boxesd              = (double*)A(4608000);
  unsigned long long* nmskey  = (unsigned long long*)A(1152000);
  unsigned* key32             = (unsigned*)A(576000);
  double* selboxd             = (double*)A(192000);
  unsigned long long* selkey  = (unsigned long long*)A(48000);
  unsigned long long* skeys   = (unsigned long long*)A(48000);
  double* sboxd               = (double*)A(192000);
  unsigned long long* rowbits = (unsigned long long*)A(6144000);
  int* eqidx                  = (int*)A(32768);

  unsigned* hist1 = histc;
  unsigned* hist2 = histc + 65536;
  int* cnt        = (int*)(histc + 131072);
  int* meta       = cnt + 2;

  hipMemsetAsync(histc, 0, (size_t)524328, stream);

  hipLaunchKernelGGL(prep_all, dim3(90), dim3(256), 0, stream,
                     Wc, Wr, WcT, WrT);
  hipLaunchKernelGGL(conv_gemm, dim3(1000), dim3(256), 0, stream, fm, W1, b1, yd);
  hipLaunchKernelGGL(head2, dim3(1000), dim3(256), 0, stream, yd, WcT, bc, WrT, br, out, scored, regd);
  hipLaunchKernelGGL(decode_hist, dim3((NANCH + 255)/256), dim3(256), 0, stream,
                     amap, scored, regd, boxesd, key32, nmskey, hist1);
  hipLaunchKernelGGL(scan_hi, dim3(1), dim3(1024), 0, stream, hist1, meta);
  hipLaunchKernelGGL(hist_lo, dim3((NANCH + 255)/256), dim3(256), 0, stream, key32, meta, hist2);
  hipLaunchKernelGGL(scan_lo, dim3(1), dim3(1024), 0, stream, hist2, meta);
  hipLaunchKernelGGL(compact_k, dim3((NANCH + 255)/256), dim3(256), 0, stream,
                     key32, nmskey, boxesd, meta, cnt, selboxd, selkey, eqidx);
  hipLaunchKernelGGL(rankeq, dim3(1), dim3(256), 0, stream,
                     scored, boxesd, nmskey, meta, cnt, eqidx, selboxd, selkey);
  hipLaunchKernelGGL(rank_scatter, dim3((PRE_NMS + 255)/256), dim3(256), 0, stream,
                     selkey, selboxd, skeys, sboxd);
  hipLaunchKernelGGL(iou_bitmap, dim3(375, 6), dim3(256), 0, stream, sboxd, rowbits);
  hipLaunchKernelGGL(greedy, dim3(1), dim3(64), 0, stream, skeys, sboxd, rowbits, out + 720000);
}

// Round 9
// 2003.348 us; speedup vs baseline: 1.2965x; 1.0732x over previous
//
#include <hip/hip_runtime.h>
#include <math.h>

#define FHh 100
#define FWw 160
#define CIN 512
#define COUT 512
#define NPIX 16000
#define NANCH 144000
#define PRE_NMS 6000
#define POST_NMS 300
#define EQCAP 8192

typedef double d4 __attribute__((ext_vector_type(4)));

// monotonic fp32 -> u32 key
__device__ __forceinline__ unsigned fkey(float x){
  unsigned b = __float_as_uint(x);
  return (b & 0x80000000u) ? ~b : (b | 0x80000000u);
}
// monotonic fp64 -> u64 key
__device__ __forceinline__ unsigned long long dkey(double x){
  unsigned long long u = (unsigned long long)__double_as_longlong(x);
  return (u & 0x8000000000000000ull) ? ~u : (u | 0x8000000000000000ull);
}
__device__ __forceinline__ unsigned long long shfl_u64(unsigned long long x, int lane){
  unsigned lo = (unsigned)x, hi = (unsigned)(x >> 32);
  lo = __shfl(lo, lane, 64);
  hi = __shfl(hi, lane, 64);
  return ((unsigned long long)hi << 32) | lo;
}

// ---------------- prep: head weights -> f64 transposed ----------------
__global__ __launch_bounds__(256) void prep_all(
    const float* __restrict__ Wc, const float* __restrict__ Wr,
    double* __restrict__ WcT, double* __restrict__ WrT)
{
  const int gid = blockIdx.x*256 + threadIdx.x;   // < 45*512 exactly (grid 90)
  const int n = gid >> 9, ci = gid & 511;
  if (n < 9) WcT[(size_t)n*512 + ci] = (double)Wc[ci*9 + n];
  else       WrT[(size_t)(n-9)*512 + ci] = (double)Wr[ci*36 + (n-9)];
}

// ---------------- 3x3 conv 512->512: A-in-LDS, B-from-L2 f64 MFMA GEMM ----------------
// r5 verified version (best conv: 1249 us, MfmaUtil 83%).
// 128x128 block tile, grid 500 (co-major); 4 waves, each 64px x 64co.
// A neighborhood (6x34 px, 16 k) staged in LDS once per kc (read-only for all 9 taps).
// B: per-lane direct global loads from f32 W1 (L2-resident, 2.36MB) + in-reg f64 cvt —
// NO LDS staging, NO per-tap barriers. Barriers: 2 per kc (Ns overwrite) = 64 total.
// Per-output MFMA order (kc,tap,k4 ascending) -> bit-identical output across r3..r8.
// Fragment maps (r1/r2-verified):
//   A: lane holds A[row=l&15][k=l>>4];  B: lane holds B[k=l>>4][col=l&15]
//   D: lane l reg i -> C[row = 4*i + (l>>4)][col = l&15]
__global__ __launch_bounds__(256, 2) void conv_gemm(
    const float* __restrict__ fm, const float* __restrict__ W1,
    const float* __restrict__ b1, double* __restrict__ yd)
{
  __shared__ double Ns[16*204];        // A[k][nr*34+nc]  (26.1 KB)

  const int bid  = blockIdx.x;
  const int cg   = bid / 125;          // 0..3 co-group
  const int tile = bid - cg*125;       // 0..124
  const int rp   = tile / 5;           // 0..24
  const int xseg = tile - rp*5;        // 0..4
  const int x0   = xseg*32;
  const int row0 = rp*4;
  const int co0  = cg*128;

  const int tid  = threadIdx.x;
  const int lane = tid & 63;
  const int kl   = lane >> 4;
  const int cl   = lane & 15;
  const int wv   = tid >> 6;
  const int wr   = wv >> 1;            // px half -> base wr*64
  const int wc   = wv & 1;             // co half -> base wc*64

  double pf[4][4];                     // A-prefetch regs (816 tasks / 256 thr = 4 iters)

  // ---- A prefetch: global f32 -> regs (f64), task t = px*4+kq, px = nr*34+nc ----
  auto APF_LOAD = [&](int kc){
    #pragma unroll
    for (int it = 0; it < 4; ++it){
      const int t  = it*256 + tid;
      const int px = t >> 2, kq = t & 3;
      const int nr = px / 34, nc = px - nr*34;
      const int row = row0 + nr - 1, col = x0 + nc - 1;
      const bool ok = (t < 816) && (row >= 0) && (row < FHh) && (col >= 0) && (col < FWw);
      if (ok){
        const float4 v = *(const float4*)(fm + ((size_t)(row*FWw + col))*CIN + kc*16 + kq*4);
        pf[it][0] = (double)v.x; pf[it][1] = (double)v.y;
        pf[it][2] = (double)v.z; pf[it][3] = (double)v.w;
      } else {
        pf[it][0] = pf[it][1] = pf[it][2] = pf[it][3] = 0.0;
      }
    }
  };
  auto APF_WRITE = [&](){
    #pragma unroll
    for (int it = 0; it < 4; ++it){
      const int t  = it*256 + tid;
      const int px = t >> 2, kq = t & 3;
      if (t < 816){
        #pragma unroll
        for (int u = 0; u < 4; ++u)
          Ns[(kq*4 + u)*204 + px] = pf[it][u];
      }
    }
  };

  d4 acc[4][4];
  #pragma unroll
  for (int mt = 0; mt < 4; ++mt)
    #pragma unroll
    for (int nt = 0; nt < 4; ++nt) acc[mt][nt] = (d4){0.0, 0.0, 0.0, 0.0};

  // prologue: stage A(kc0)
  APF_LOAD(0);
  APF_WRITE();
  __syncthreads();

  const int abase_t = kl*204 + cl;     // per-thread A base in Ns
  const float* Bbase = W1 + (size_t)kl*512 + co0 + wc*64 + cl;   // + (tap*512+kc*16)*512

  #pragma unroll 1
  for (int kc = 0; kc < 32; ++kc){
    #pragma unroll 1
    for (int tap = 0; tap < 9; ++tap){
      if (tap == 7 && kc < 31) APF_LOAD(kc + 1);
      // ---- B fragment: 16 coalesced f32 loads from L2 + exact cvt to f64 ----
      const float* Bt = Bbase + ((size_t)(tap*512 + kc*16))*512;
      double breg[16];
      #pragma unroll
      for (int k4 = 0; k4 < 4; ++k4)
        #pragma unroll
        for (int nt = 0; nt < 4; ++nt)
          breg[k4*4 + nt] = (double)Bt[k4*2048 + nt*16];
      // ---- A pointer for this tap ----
      const int ty = tap / 3;
      const int dy = ty - 1, dx = (tap - ty*3) - 1;
      const double* An = Ns + abase_t + (wr*2 + dy + 1)*34 + (dx + 1);
      __builtin_amdgcn_s_setprio(1);
      #pragma unroll
      for (int k4 = 0; k4 < 4; ++k4){
        const double a0 = An[k4*4*204 + 0*34 + 0];    // mt0: (r+0, c0)
        const double a1 = An[k4*4*204 + 0*34 + 16];   // mt1: (r+0, c16)
        const double a2 = An[k4*4*204 + 1*34 + 0];    // mt2: (r+1, c0)
        const double a3 = An[k4*4*204 + 1*34 + 16];   // mt3: (r+1, c16)
        const double b0 = breg[k4*4 + 0];
        const double b1v= breg[k4*4 + 1];
        const double b2 = breg[k4*4 + 2];
        const double b3 = breg[k4*4 + 3];
        acc[0][0] = __builtin_amdgcn_mfma_f64_16x16x4f64(a0, b0,  acc[0][0], 0, 0, 0);
        acc[0][1] = __builtin_amdgcn_mfma_f64_16x16x4f64(a0, b1v, acc[0][1], 0, 0, 0);
        acc[0][2] = __builtin_amdgcn_mfma_f64_16x16x4f64(a0, b2,  acc[0][2], 0, 0, 0);
        acc[0][3] = __builtin_amdgcn_mfma_f64_16x16x4f64(a0, b3,  acc[0][3], 0, 0, 0);
        acc[1][0] = __builtin_amdgcn_mfma_f64_16x16x4f64(a1, b0,  acc[1][0], 0, 0, 0);
        acc[1][1] = __builtin_amdgcn_mfma_f64_16x16x4f64(a1, b1v, acc[1][1], 0, 0, 0);
        acc[1][2] = __builtin_amdgcn_mfma_f64_16x16x4f64(a1, b2,  acc[1][2], 0, 0, 0);
        acc[1][3] = __builtin_amdgcn_mfma_f64_16x16x4f64(a1, b3,  acc[1][3], 0, 0, 0);
        acc[2][0] = __builtin_amdgcn_mfma_f64_16x16x4f64(a2, b0,  acc[2][0], 0, 0, 0);
        acc[2][1] = __builtin_amdgcn_mfma_f64_16x16x4f64(a2, b1v, acc[2][1], 0, 0, 0);
        acc[2][2] = __builtin_amdgcn_mfma_f64_16x16x4f64(a2, b2,  acc[2][2], 0, 0, 0);
        acc[2][3] = __builtin_amdgcn_mfma_f64_16x16x4f64(a2, b3,  acc[2][3], 0, 0, 0);
        acc[3][0] = __builtin_amdgcn_mfma_f64_16x16x4f64(a3, b0,  acc[3][0], 0, 0, 0);
        acc[3][1] = __builtin_amdgcn_mfma_f64_16x16x4f64(a3, b1v, acc[3][1], 0, 0, 0);
        acc[3][2] = __builtin_amdgcn_mfma_f64_16x16x4f64(a3, b2,  acc[3][2], 0, 0, 0);
        acc[3][3] = __builtin_amdgcn_mfma_f64_16x16x4f64(a3, b3,  acc[3][3], 0, 0, 0);
      }
      __builtin_amdgcn_s_setprio(0);
    }
    // kc boundary: all waves done reading Ns(kc) -> overwrite with kc+1
    __syncthreads();
    if (kc < 31){
      APF_WRITE();
      __syncthreads();
    }
  }
  // epilogue: bias + relu + store; D row = 4*reg + (lane>>4)
  double bb[4];
  #pragma unroll
  for (int nt = 0; nt < 4; ++nt) bb[nt] = (double)b1[co0 + wc*64 + nt*16 + cl];
  #pragma unroll
  for (int mt = 0; mt < 4; ++mt){
    #pragma unroll
    for (int i = 0; i < 4; ++i){
      const int pxl = wr*64 + mt*16 + 4*i + kl;
      const int gpx = (row0 + (pxl >> 5))*FWw + x0 + (pxl & 31);
      double* yrow = yd + (size_t)gpx*CIN + co0 + wc*64 + cl;
      #pragma unroll
      for (int nt = 0; nt < 4; ++nt){
        yrow[nt*16] = fmax(acc[mt][nt][i] + bb[nt], 0.0);
      }
    }
  }
}

// ---------------- 1x1 heads (f64): thread = one output n x 4 px ----------------
__global__ __launch_bounds__(256) void head2(
    const double* __restrict__ yd, const double* __restrict__ WcT, const float* __restrict__ bc,
    const double* __restrict__ WrT, const float* __restrict__ br,
    float* __restrict__ out, double* __restrict__ scored, double* __restrict__ regd)
{
  __shared__ double yl[8192];          // 16 px x 512
  const int bid = blockIdx.x, t = threadIdx.x;
  const double2* src = (const double2*)(yd + (size_t)bid * 8192);
  double2* dst = (double2*)yl;
  for (int j = t; j < 4096; j += 256) dst[j] = src[j];
  __syncthreads();
  if (t < 180){
    const int n  = t % 45;
    const int pq = t / 45;             // 0..3 -> px pq*4..pq*4+3
    const double* w = (n < 9) ? (WcT + (size_t)n*512) : (WrT + (size_t)(n-9)*512);
    const double* y0 = yl + (pq*4+0)*512;
    const double* y1 = yl + (pq*4+1)*512;
    const double* y2 = yl + (pq*4+2)*512;
    const double* y3 = yl + (pq*4+3)*512;
    double s0=0.0, s1=0.0, s2=0.0, s3=0.0;
    for (int ci = 0; ci < 512; ++ci){
      const double wv = w[ci];
      s0 = fma(y0[ci], wv, s0);
      s1 = fma(y1[ci], wv, s1);
      s2 = fma(y2[ci], wv, s2);
      s3 = fma(y3[ci], wv, s3);
    }
    const double sv[4] = {s0, s1, s2, s3};
    if (n < 9){
      const double bb = (double)bc[n];
      #pragma unroll
      for (int u = 0; u < 4; ++u){
        const double s = sv[u] + bb;
        const double sig = 1.0 / (1.0 + exp(-s));
        const int gi = (bid*16 + pq*4 + u)*9 + n;
        out[gi] = (float)sig;
        scored[gi] = sig;
      }
    } else {
      const int m = n - 9;
      const double bb = (double)br[m];
      #pragma unroll
      for (int u = 0; u < 4; ++u){
        const double s = sv[u] + bb;
        const int gi = (bid*16 + pq*4 + u)*36 + m;
        out[144000 + gi] = (float)s;
        regd[gi] = s;
      }
    }
  }
}

// ---------------- decode + clip + min-size (f64) + fused hi-histogram ----------------
__global__ __launch_bounds__(256) void decode_hist(
    const float* __restrict__ amap, const double* __restrict__ scored,
    const double* __restrict__ regd, double* __restrict__ boxesd,
    unsigned* __restrict__ key32, unsigned long long* __restrict__ nmskey,
    unsigned* __restrict__ hist)
{
  const int i = blockIdx.x*256 + threadIdx.x;
  if (i >= NANCH) return;
  const double a0=(double)amap[4*i+0], a1=(double)amap[4*i+1];
  const double a2=(double)amap[4*i+2], a3=(double)amap[4*i+3];
  const double d0=regd[4*i+0], d1=regd[4*i+1], d2=regd[4*i+2], d3=regd[4*i+3];
  const double ah = a2 - a0, aw = a3 - a1;
  const double cy = a0 + 0.5*ah + d0*ah;
  const double cx = a1 + 0.5*aw + d1*aw;
  const double h = ah * exp(d2), w = aw * exp(d3);
  double y1 = cy - 0.5*h, x1 = cx - 0.5*w, y2 = cy + 0.5*h, x2 = cx + 0.5*w;
  y1 = fmax(y1, 0.0); x1 = fmax(x1, 0.0);
  y2 = fmin(y2, 1600.0); x2 = fmin(x2, 2560.0);
  boxesd[4*i+0]=y1; boxesd[4*i+1]=x1; boxesd[4*i+2]=y2; boxesd[4*i+3]=x2;
  const double obj = scored[i];
  const bool ok = (y2 - y1 >= 16.0) && (x2 - x1 >= 16.0);
  const unsigned k32 = fkey((float)obj);
  key32[i] = k32;
  nmskey[i] = ok ? dkey(obj) : dkey(-1e9);
  atomicAdd(&hist[k32 >> 16], 1u);
}

// ---------------- top-6000 radix select on f32-rounded keys ----------------
__global__ __launch_bounds__(1024) void scan_hi(const unsigned* __restrict__ hist, int* __restrict__ meta){
  __shared__ unsigned part[1024];
  const int t = threadIdx.x;
  unsigned s = 0;
  for (int j = 0; j < 64; ++j) s += hist[65535 - (t*64 + j)];
  part[t] = s;
  __syncthreads();
  for (int off = 1; off < 1024; off <<= 1){
    unsigned v = (t >= off) ? part[t - off] : 0u;
    __syncthreads();
    part[t] += v;
    __syncthreads();
  }
  const unsigned incl = part[t], excl = incl - s;
  if (excl < PRE_NMS && incl >= PRE_NMS){
    unsigned cum = excl;
    for (int j = 0; j < 64; ++j){
      const int bin = 65535 - (t*64 + j);
      const unsigned c = hist[bin];
      if (cum + c >= PRE_NMS){ meta[0] = bin; meta[1] = (int)cum; break; }
      cum += c;
    }
  }
}

__global__ __launch_bounds__(256) void hist_lo(const unsigned* __restrict__ key,
                                               const int* __restrict__ meta, unsigned* __restrict__ hist){
  const int i = blockIdx.x*256 + threadIdx.x;
  if (i < NANCH){
    const unsigned k = key[i];
    if ((int)(k >> 16) == meta[0]) atomicAdd(&hist[k & 0xFFFFu], 1u);
  }
}

__global__ __launch_bounds__(1024) void scan_lo(const unsigned* __restrict__ hist, int* __restrict__ meta){
  __shared__ unsigned part[1024];
  const int t = threadIdx.x;
  const unsigned G0 = (unsigned)meta[1];
  unsigned s = 0;
  for (int j = 0; j < 64; ++j) s += hist[65535 - (t*64 + j)];
  part[t] = s;
  __syncthreads();
  for (int off = 1; off < 1024; off <<= 1){
    unsigned v = (t >= off) ? part[t - off] : 0u;
    __syncthreads();
    part[t] += v;
    __syncthreads();
  }
  const unsigned incl = G0 + part[t], excl = incl - s;
  if (excl < PRE_NMS && incl >= PRE_NMS){
    unsigned cum = excl;
    for (int j = 0; j < 64; ++j){
      const int bin = 65535 - (t*64 + j);
      const unsigned c = hist[bin];
      if (cum + c >= PRE_NMS){
        meta[2] = (int)(((unsigned)meta[0] << 16) | (unsigned)bin);
        meta[3] = (int)cum;
        meta[4] = PRE_NMS - (int)cum;
        break;
      }
      cum += c;
    }
  }
}

__global__ __launch_bounds__(256) void compact_k(
    const unsigned* __restrict__ key, const unsigned long long* __restrict__ nmskey,
    const double* __restrict__ boxesd, const int* __restrict__ meta,
    int* __restrict__ cnt, double* __restrict__ selboxd,
    unsigned long long* __restrict__ selkey, int* __restrict__ eqidx)
{
  const int i = blockIdx.x*256 + threadIdx.x;
  if (i >= NANCH) return;
  const unsigned k = key[i];
  const unsigned T = (unsigned)meta[2];
  if (k > T){
    const int s = atomicAdd(&cnt[0], 1);
    selboxd[4*s+0]=boxesd[4*i+0]; selboxd[4*s+1]=boxesd[4*i+1];
    selboxd[4*s+2]=boxesd[4*i+2]; selboxd[4*s+3]=boxesd[4*i+3];
    selkey[s] = nmskey[i];
  } else if (k == T){
    const int e = atomicAdd(&cnt[1], 1);
    if (e < EQCAP) eqidx[e] = i;
  }
}

__global__ __launch_bounds__(256) void rankeq(
    const double* __restrict__ scored, const double* __restrict__ boxesd,
    const unsigned long long* __restrict__ nmskey,
    const int* __restrict__ meta, const int* __restrict__ cnt,
    const int* __restrict__ eqidx, double* __restrict__ selboxd,
    unsigned long long* __restrict__ selkey)
{
  __shared__ int eq[EQCAP];
  const int t = threadIdx.x;
  int E = cnt[1]; if (E > EQCAP) E = EQCAP;
  const int R = meta[4], G2 = meta[3];
  for (int j = t; j < E; j += 256) eq[j] = eqidx[j];
  __syncthreads();
  for (int j = t; j < E; j += 256){
    const int my = eq[j];
    const double smy = scored[my];
    int rank = 0;
    for (int k2 = 0; k2 < E; ++k2){
      const int ok = eq[k2];
      const double sk = scored[ok];
      rank += ((sk > smy) || (sk == smy && ok < my)) ? 1 : 0;
    }
    if (rank < R){
      const int s = G2 + rank;
      selboxd[4*s+0]=boxesd[4*my+0]; selboxd[4*s+1]=boxesd[4*my+1];
      selboxd[4*s+2]=boxesd[4*my+2]; selboxd[4*s+3]=boxesd[4*my+3];
      selkey[s] = nmskey[my];
    }
  }
}

// ---------------- rank-by-counting scatter ----------------
__global__ __launch_bounds__(256) void rank_scatter(
    const unsigned long long* __restrict__ selkey, const double* __restrict__ selboxd,
    unsigned long long* __restrict__ skeys, double* __restrict__ sboxd)
{
  __shared__ unsigned long long k[PRE_NMS];
  const int t = threadIdx.x;
  for (int j = t; j < PRE_NMS; j += 256) k[j] = selkey[j];
  __syncthreads();
  const int j = blockIdx.x*256 + t;
  if (j >= PRE_NMS) return;
  const unsigned long long kj = k[j];
  int r = 0;
  for (int i = 0; i < PRE_NMS; i += 4){
    r += (int)((k[i+0] > kj) || (k[i+0] == kj && (i+0) < j));
    r += (int)((k[i+1] > kj) || (k[i+1] == kj && (i+1) < j));
    r += (int)((k[i+2] > kj) || (k[i+2] == kj && (i+2) < j));
    r += (int)((k[i+3] > kj) || (k[i+3] == kj && (i+3) < j));
  }
  skeys[r] = kj;
  sboxd[(size_t)r*4+0] = selboxd[(size_t)j*4+0];
  sboxd[(size_t)r*4+1] = selboxd[(size_t)j*4+1];
  sboxd[(size_t)r*4+2] = selboxd[(size_t)j*4+2];
  sboxd[(size_t)r*4+3] = selboxd[(size_t)j*4+3];
}

// ---------------- 6000x6000 IOU suppression bitmap ----------------
__global__ __launch_bounds__(256) void iou_bitmap(
    const double* __restrict__ sboxd, unsigned long long* __restrict__ rowbits)
{
  __shared__ double cbx[4096];           // 1024 col boxes
  const int g = blockIdx.y;              // 0..5 word-groups
  const int r0 = blockIdx.x * 16;
  const int t = threadIdx.x;
  const int cbase = g * 1024;
  for (int e = t; e < 4096; e += 256){
    const int bi = cbase + (e >> 2);
    cbx[e] = (bi < PRE_NMS) ? sboxd[(size_t)bi*4 + (e & 3)] : 0.0;
  }
  __syncthreads();
  const int r = r0 + (t >> 4);
  const int w = t & 15;
  const double by1 = sboxd[(size_t)r*4+0], bx1 = sboxd[(size_t)r*4+1];
  const double by2 = sboxd[(size_t)r*4+2], bx2 = sboxd[(size_t)r*4+3];
  const double a1 = fmax(by2-by1, 0.0) * fmax(bx2-bx1, 0.0);
  unsigned long long bits = 0ull;
  for (int b = 0; b < 64; ++b){
    const int bcol = (b + w) & 63;
    const int j = cbase + w*64 + bcol;
    if (j < PRE_NMS){
      const int ce = (w*64 + bcol)*4;
      const double c0 = cbx[ce+0], c1 = cbx[ce+1], c2 = cbx[ce+2], c3 = cbx[ce+3];
      const double yy1 = fmax(by1, c0), xx1 = fmax(bx1, c1);
      const double yy2 = fmin(by2, c2), xx2 = fmin(bx2, c3);
      const double inter = fmax(yy2-yy1, 0.0) * fmax(xx2-xx1, 0.0);
      const double a2 = fmax(c2-c0, 0.0) * fmax(c3-c1, 0.0);
      const double iou = inter / (a1 + a2 - inter + 1e-8);
      if (iou > 0.7) bits |= (1ull << bcol);
    }
  }
  rowbits[(size_t)r*128 + g*16 + w] = bits;
}

// ---------------- greedy scan: word-skipping (ctz) over suppression bitmap ----------------
// Same greedy order/semantics as the serial-bit version; non-accepted boxes cost zero
// iterations (skipped via ffsll). State: lane t holds words t (s0) and 64+t (s1).
__global__ __launch_bounds__(64) void greedy(
    const unsigned long long* __restrict__ skeys, const double* __restrict__ sboxd,
    const unsigned long long* __restrict__ rowbits, float* __restrict__ outp)
{
  const int t = threadIdx.x;
  const unsigned long long KEYTH = dkey(-5.0e8);
  int bad = PRE_NMS;
  for (int j = t; j < PRE_NMS; j += 64){
    if (skeys[j] <= KEYTH){ bad = j; break; }
  }
  #pragma unroll
  for (int off = 32; off > 0; off >>= 1){
    const int o = __shfl_down(bad, off, 64);
    bad = (o < bad) ? o : bad;
  }
  const int ilim = __builtin_amdgcn_readfirstlane(bad);

  // pre-suppress indices >= ilim (mask of bits b where word*64+b >= ilim)
  auto maskfrom = [](int start) -> unsigned long long {
    if (start <= 0) return ~0ull;
    if (start >= 64) return 0ull;
    return (~0ull) << start;
  };
  unsigned long long s0 = maskfrom(ilim - t*64);
  unsigned long long s1 = (t < 30) ? maskfrom(ilim - (64 + t)*64) : ~0ull;

  int emitted = 0;
  for (int w = 0; w < 94 && emitted < POST_NMS; ++w){
    const unsigned long long sw = (w < 64) ? shfl_u64(s0, w) : shfl_u64(s1, w - 64);
    unsigned long long avail = ~sw;          // uniform across lanes
    while (avail && emitted < POST_NMS){
      const int b = __ffsll((long long)avail) - 1;
      const int i = w*64 + b;
      if (t < 4) outp[4*emitted + t] = (float)sboxd[(size_t)i*4 + t];
      const unsigned long long r0 = rowbits[(size_t)i*128 + t];
      const unsigned long long r1 = (t < 30) ? rowbits[(size_t)i*128 + 64 + t] : 0ull;
      s0 |= r0; s1 |= r1;
      ++emitted;
      const unsigned long long rw = (w < 64) ? shfl_u64(r0, w) : shfl_u64(r1, w - 64);
      avail &= ~rw;
      avail &= ~(1ull << b);
    }
  }
  for (int r = emitted; r < POST_NMS; ++r)
    if (t < 4) outp[4*r + t] = 0.f;
}

extern "C" void kernel_launch(void* const* d_in, const int* in_sizes, int n_in,
                              void* d_out, int out_size, void* d_ws, size_t ws_size,
                              hipStream_t stream)
{
  const float* fm   = (const float*)d_in[1];
  const float* amap = (const float*)d_in[2];
  const float* W1   = (const float*)d_in[4];
  const float* b1   = (const float*)d_in[5];
  const float* Wc   = (const float*)d_in[6];
  const float* bc   = (const float*)d_in[7];
  const float* Wr   = (const float*)d_in[8];
  const float* br   = (const float*)d_in[9];
  float* out = (float*)d_out;

  char* base = (char*)d_ws;
  size_t off = 0;
  auto A = [&](size_t n) -> char* {
    char* p = base + off;
    off = (off + n + 255) & ~(size_t)255;
    return p;
  };
  double* yd      = (double*)A(65536000);
  double* WcT     = (double*)A(36864);
  double* WrT     = (double*)A(147456);
  double* scored  = (double*)A(1152000);
  double* regd    = (double*)A(4608000);
  unsigned* histc = (unsigned*)A(524328);        // hist1|hist2|cnt|meta contiguous
  double* boxesd              = (double*)A(4608000);
  unsigned long long* nmskey  = (unsigned long long*)A(1152000);
  unsigned* key32             = (unsigned*)A(576000);
  double* selboxd             = (double*)A(192000);
  unsigned long long* selkey  = (unsigned long long*)A(48000);
  unsigned long long* skeys   = (unsigned long long*)A(48000);
  double* sboxd               = (double*)A(192000);
  unsigned long long* rowbits = (unsigned long long*)A(6144000);
  int* eqidx                  = (int*)A(32768);

  unsigned* hist1 = histc;
  unsigned* hist2 = histc + 65536;
  int* cnt        = (int*)(histc + 131072);
  int* meta       = cnt + 2;

  hipMemsetAsync(histc, 0, (size_t)524328, stream);

  hipLaunchKernelGGL(prep_all, dim3(90), dim3(256), 0, stream,
                     Wc, Wr, WcT, WrT);
  hipLaunchKernelGGL(conv_gemm, dim3(500), dim3(256), 0, stream, fm, W1, b1, yd);
  hipLaunchKernelGGL(head2, dim3(1000), dim3(256), 0, stream, yd, WcT, bc, WrT, br, out, scored, regd);
  hipLaunchKernelGGL(decode_hist, dim3((NANCH + 255)/256), dim3(256), 0, stream,
                     amap, scored, regd, boxesd, key32, nmskey, hist1);
  hipLaunchKernelGGL(scan_hi, dim3(1), dim3(1024), 0, stream, hist1, meta);
  hipLaunchKernelGGL(hist_lo, dim3((NANCH + 255)/256), dim3(256), 0, stream, key32, meta, hist2);
  hipLaunchKernelGGL(scan_lo, dim3(1), dim3(1024), 0, stream, hist2, meta);
  hipLaunchKernelGGL(compact_k, dim3((NANCH + 255)/256), dim3(256), 0, stream,
                     key32, nmskey, boxesd, meta, cnt, selboxd, selkey, eqidx);
  hipLaunchKernelGGL(rankeq, dim3(1), dim3(256), 0, stream,
                     scored, boxesd, nmskey, meta, cnt, eqidx, selboxd, selkey);
  hipLaunchKernelGGL(rank_scatter, dim3((PRE_NMS + 255)/256), dim3(256), 0, stream,
                     selkey, selboxd, skeys, sboxd);
  hipLaunchKernelGGL(iou_bitmap, dim3(375, 6), dim3(256), 0, stream, sboxd, rowbits);
  hipLaunchKernelGGL(greedy, dim3(1), dim3(64), 0, stream, skeys, sboxd, rowbits, out + 720000);
}

// Round 10
// 1939.808 us; speedup vs baseline: 1.3390x; 1.0328x over previous
//
#include <hip/hip_runtime.h>
#include <math.h>

#define FHh 100
#define FWw 160
#define CIN 512
#define COUT 512
#define NPIX 16000
#define NANCH 144000
#define PRE_NMS 6000
#define POST_NMS 300
#define EQCAP 8192

typedef double d4 __attribute__((ext_vector_type(4)));

// monotonic fp32 -> u32 key
__device__ __forceinline__ unsigned fkey(float x){
  unsigned b = __float_as_uint(x);
  return (b & 0x80000000u) ? ~b : (b | 0x80000000u);
}
// monotonic fp64 -> u64 key
__device__ __forceinline__ unsigned long long dkey(double x){
  unsigned long long u = (unsigned long long)__double_as_longlong(x);
  return (u & 0x8000000000000000ull) ? ~u : (u | 0x8000000000000000ull);
}
__device__ __forceinline__ unsigned long long shfl_u64(unsigned long long x, int lane){
  unsigned lo = (unsigned)x, hi = (unsigned)(x >> 32);
  lo = __shfl(lo, lane, 64);
  hi = __shfl(hi, lane, 64);
  return ((unsigned long long)hi << 32) | lo;
}

// ---------------- prep: head weights -> f64 B-layout WT[512][48] ----------------
// WT[k][n] = n<9 ? Wc[k*9+n] : n<45 ? Wr[k*36+(n-9)] : 0   (exact f32->f64)
__global__ __launch_bounds__(256) void prep_all(
    const float* __restrict__ Wc, const float* __restrict__ Wr,
    double* __restrict__ WT)
{
  const int gid = blockIdx.x*256 + threadIdx.x;   // < 512*48 = 24576 (grid 96)
  const int k = gid / 48, n = gid - k*48;
  double v = 0.0;
  if (n < 9)       v = (double)Wc[k*9 + n];
  else if (n < 45) v = (double)Wr[k*36 + (n-9)];
  WT[gid] = v;
}

// ---------------- 3x3 conv 512->512: A-in-LDS, B-from-L2 f64 MFMA GEMM ----------------
// r5 verified version (best conv: 1249 us, MfmaUtil 83%).
// 128x128 block tile, grid 500 (co-major); 4 waves, each 64px x 64co.
// A neighborhood (6x34 px, 16 k) staged in LDS once per kc (read-only for all 9 taps).
// B: per-lane direct global loads from f32 W1 (L2-resident, 2.36MB) + in-reg f64 cvt —
// NO LDS staging, NO per-tap barriers. Barriers: 2 per kc (Ns overwrite) = 64 total.
// Per-output MFMA order (kc,tap,k4 ascending) -> bit-identical output across r3..r9.
// Fragment maps (r1/r2-verified):
//   A: lane holds A[row=l&15][k=l>>4];  B: lane holds B[k=l>>4][col=l&15]
//   D: lane l reg i -> C[row = 4*i + (l>>4)][col = l&15]
__global__ __launch_bounds__(256, 2) void conv_gemm(
    const float* __restrict__ fm, const float* __restrict__ W1,
    const float* __restrict__ b1, double* __restrict__ yd)
{
  __shared__ double Ns[16*204];        // A[k][nr*34+nc]  (26.1 KB)

  const int bid  = blockIdx.x;
  const int cg   = bid / 125;          // 0..3 co-group
  const int tile = bid - cg*125;       // 0..124
  const int rp   = tile / 5;           // 0..24
  const int xseg = tile - rp*5;        // 0..4
  const int x0   = xseg*32;
  const int row0 = rp*4;
  const int co0  = cg*128;

  const int tid  = threadIdx.x;
  const int lane = tid & 63;
  const int kl   = lane >> 4;
  const int cl   = lane & 15;
  const int wv   = tid >> 6;
  const int wr   = wv >> 1;            // px half -> base wr*64
  const int wc   = wv & 1;             // co half -> base wc*64

  double pf[4][4];                     // A-prefetch regs (816 tasks / 256 thr = 4 iters)

  // ---- A prefetch: global f32 -> regs (f64), task t = px*4+kq, px = nr*34+nc ----
  auto APF_LOAD = [&](int kc){
    #pragma unroll
    for (int it = 0; it < 4; ++it){
      const int t  = it*256 + tid;
      const int px = t >> 2, kq = t & 3;
      const int nr = px / 34, nc = px - nr*34;
      const int row = row0 + nr - 1, col = x0 + nc - 1;
      const bool ok = (t < 816) && (row >= 0) && (row < FHh) && (col >= 0) && (col < FWw);
      if (ok){
        const float4 v = *(const float4*)(fm + ((size_t)(row*FWw + col))*CIN + kc*16 + kq*4);
        pf[it][0] = (double)v.x; pf[it][1] = (double)v.y;
        pf[it][2] = (double)v.z; pf[it][3] = (double)v.w;
      } else {
        pf[it][0] = pf[it][1] = pf[it][2] = pf[it][3] = 0.0;
      }
    }
  };
  auto APF_WRITE = [&](){
    #pragma unroll
    for (int it = 0; it < 4; ++it){
      const int t  = it*256 + tid;
      const int px = t >> 2, kq = t & 3;
      if (t < 816){
        #pragma unroll
        for (int u = 0; u < 4; ++u)
          Ns[(kq*4 + u)*204 + px] = pf[it][u];
      }
    }
  };

  d4 acc[4][4];
  #pragma unroll
  for (int mt = 0; mt < 4; ++mt)
    #pragma unroll
    for (int nt = 0; nt < 4; ++nt) acc[mt][nt] = (d4){0.0, 0.0, 0.0, 0.0};

  // prologue: stage A(kc0)
  APF_LOAD(0);
  APF_WRITE();
  __syncthreads();

  const int abase_t = kl*204 + cl;     // per-thread A base in Ns
  const float* Bbase = W1 + (size_t)kl*512 + co0 + wc*64 + cl;   // + (tap*512+kc*16)*512

  #pragma unroll 1
  for (int kc = 0; kc < 32; ++kc){
    #pragma unroll 1
    for (int tap = 0; tap < 9; ++tap){
      if (tap == 7 && kc < 31) APF_LOAD(kc + 1);
      // ---- B fragment: 16 coalesced f32 loads from L2 + exact cvt to f64 ----
      const float* Bt = Bbase + ((size_t)(tap*512 + kc*16))*512;
      double breg[16];
      #pragma unroll
      for (int k4 = 0; k4 < 4; ++k4)
        #pragma unroll
        for (int nt = 0; nt < 4; ++nt)
          breg[k4*4 + nt] = (double)Bt[k4*2048 + nt*16];
      // ---- A pointer for this tap ----
      const int ty = tap / 3;
      const int dy = ty - 1, dx = (tap - ty*3) - 1;
      const double* An = Ns + abase_t + (wr*2 + dy + 1)*34 + (dx + 1);
      __builtin_amdgcn_s_setprio(1);
      #pragma unroll
      for (int k4 = 0; k4 < 4; ++k4){
        const double a0 = An[k4*4*204 + 0*34 + 0];    // mt0: (r+0, c0)
        const double a1 = An[k4*4*204 + 0*34 + 16];   // mt1: (r+0, c16)
        const double a2 = An[k4*4*204 + 1*34 + 0];    // mt2: (r+1, c0)
        const double a3 = An[k4*4*204 + 1*34 + 16];   // mt3: (r+1, c16)
        const double b0 = breg[k4*4 + 0];
        const double b1v= breg[k4*4 + 1];
        const double b2 = breg[k4*4 + 2];
        const double b3 = breg[k4*4 + 3];
        acc[0][0] = __builtin_amdgcn_mfma_f64_16x16x4f64(a0, b0,  acc[0][0], 0, 0, 0);
        acc[0][1] = __builtin_amdgcn_mfma_f64_16x16x4f64(a0, b1v, acc[0][1], 0, 0, 0);
        acc[0][2] = __builtin_amdgcn_mfma_f64_16x16x4f64(a0, b2,  acc[0][2], 0, 0, 0);
        acc[0][3] = __builtin_amdgcn_mfma_f64_16x16x4f64(a0, b3,  acc[0][3], 0, 0, 0);
        acc[1][0] = __builtin_amdgcn_mfma_f64_16x16x4f64(a1, b0,  acc[1][0], 0, 0, 0);
        acc[1][1] = __builtin_amdgcn_mfma_f64_16x16x4f64(a1, b1v, acc[1][1], 0, 0, 0);
        acc[1][2] = __builtin_amdgcn_mfma_f64_16x16x4f64(a1, b2,  acc[1][2], 0, 0, 0);
        acc[1][3] = __builtin_amdgcn_mfma_f64_16x16x4f64(a1, b3,  acc[1][3], 0, 0, 0);
        acc[2][0] = __builtin_amdgcn_mfma_f64_16x16x4f64(a2, b0,  acc[2][0], 0, 0, 0);
        acc[2][1] = __builtin_amdgcn_mfma_f64_16x16x4f64(a2, b1v, acc[2][1], 0, 0, 0);
        acc[2][2] = __builtin_amdgcn_mfma_f64_16x16x4f64(a2, b2,  acc[2][2], 0, 0, 0);
        acc[2][3] = __builtin_amdgcn_mfma_f64_16x16x4f64(a2, b3,  acc[2][3], 0, 0, 0);
        acc[3][0] = __builtin_amdgcn_mfma_f64_16x16x4f64(a3, b0,  acc[3][0], 0, 0, 0);
        acc[3][1] = __builtin_amdgcn_mfma_f64_16x16x4f64(a3, b1v, acc[3][1], 0, 0, 0);
        acc[3][2] = __builtin_amdgcn_mfma_f64_16x16x4f64(a3, b2,  acc[3][2], 0, 0, 0);
        acc[3][3] = __builtin_amdgcn_mfma_f64_16x16x4f64(a3, b3,  acc[3][3], 0, 0, 0);
      }
      __builtin_amdgcn_s_setprio(0);
    }
    // kc boundary: all waves done reading Ns(kc) -> overwrite with kc+1
    __syncthreads();
    if (kc < 31){
      APF_WRITE();
      __syncthreads();
    }
  }
  // epilogue: bias + relu + store; D row = 4*reg + (lane>>4)
  double bb[4];
  #pragma unroll
  for (int nt = 0; nt < 4; ++nt) bb[nt] = (double)b1[co0 + wc*64 + nt*16 + cl];
  #pragma unroll
  for (int mt = 0; mt < 4; ++mt){
    #pragma unroll
    for (int i = 0; i < 4; ++i){
      const int pxl = wr*64 + mt*16 + 4*i + kl;
      const int gpx = (row0 + (pxl >> 5))*FWw + x0 + (pxl & 31);
      double* yrow = yd + (size_t)gpx*CIN + co0 + wc*64 + cl;
      #pragma unroll
      for (int nt = 0; nt < 4; ++nt){
        yrow[nt*16] = fmax(acc[mt][nt][i] + bb[nt], 0.0);
      }
    }
  }
}

// ---------------- 1x1 heads as f64 MFMA GEMM: [16px x 512] x [512 x 48] ----------------
// 1 wave per block, 16 px; yd staged to LDS in 4 K-chunks of 128 (pad 130 -> <=2-way
// bank aliasing, free); 3 n-tiles x 32 K4-steps/chunk = 384 mfma_f64_16x16x4.
// B from WT[512][48] (L2-resident 196KB, coalesced 4x128B per load).
// Fragment maps as conv (r1-verified). K order: chunk-major, k ascending.
__global__ __launch_bounds__(64) void head2(
    const double* __restrict__ yd, const double* __restrict__ WT,
    const float* __restrict__ bc, const float* __restrict__ br,
    float* __restrict__ out, double* __restrict__ scored, double* __restrict__ regd)
{
  __shared__ double yl[16*130];        // 16 px x 128 k, padded (16.6 KB)
  const int bid = blockIdx.x;          // px base = bid*16
  const int t   = threadIdx.x;         // 0..63
  const int kl  = t >> 4;              // 0..3
  const int cl  = t & 15;              // 0..15

  d4 acc[3];
  acc[0] = (d4){0.0,0.0,0.0,0.0};
  acc[1] = (d4){0.0,0.0,0.0,0.0};
  acc[2] = (d4){0.0,0.0,0.0,0.0};

  const double2* src = (const double2*)(yd + (size_t)bid*8192);

  #pragma unroll 1
  for (int c = 0; c < 4; ++c){
    // stage 16px x 128k chunk: j-th iteration stages px row j (64 double2, coalesced)
    #pragma unroll
    for (int j = 0; j < 16; ++j){
      const double2 v = src[(size_t)j*256 + c*64 + t];
      *(double2*)&yl[j*130 + t*2] = v;
    }
    __syncthreads();
    const double* arow = yl + cl*130 + kl;        // + 4*k4
    const double* brow = WT + ((size_t)c*128 + kl)*48 + cl;   // + 4*k4*48
    #pragma unroll 8
    for (int k4 = 0; k4 < 32; ++k4){
      const double a  = arow[4*k4];
      const double b0 = brow[(size_t)4*k4*48 + 0];
      const double b1 = brow[(size_t)4*k4*48 + 16];
      const double b2 = brow[(size_t)4*k4*48 + 32];
      acc[0] = __builtin_amdgcn_mfma_f64_16x16x4f64(a, b0, acc[0], 0, 0, 0);
      acc[1] = __builtin_amdgcn_mfma_f64_16x16x4f64(a, b1, acc[1], 0, 0, 0);
      acc[2] = __builtin_amdgcn_mfma_f64_16x16x4f64(a, b2, acc[2], 0, 0, 0);
    }
    __syncthreads();
  }

  // epilogue: D row = 4*reg + (lane>>4) -> px; col = cl -> n
  const int pxb = bid*16;
  #pragma unroll
  for (int nb = 0; nb < 3; ++nb){
    const int n = nb*16 + cl;
    #pragma unroll
    for (int i = 0; i < 4; ++i){
      const int gpx = pxb + 4*i + kl;
      const double s0 = acc[nb][i];
      if (n < 9){
        const double s = s0 + (double)bc[n];
        const double sig = 1.0 / (1.0 + exp(-s));
        out[gpx*9 + n] = (float)sig;
        scored[gpx*9 + n] = sig;
      } else if (n < 45){
        const int m = n - 9;
        const double s = s0 + (double)br[m];
        out[144000 + gpx*36 + m] = (float)s;
        regd[gpx*36 + m] = s;
      }
    }
  }
}

// ---------------- decode + clip + min-size (f64) + fused hi-histogram ----------------
__global__ __launch_bounds__(256) void decode_hist(
    const float* __restrict__ amap, const double* __restrict__ scored,
    const double* __restrict__ regd, double* __restrict__ boxesd,
    unsigned* __restrict__ key32, unsigned long long* __restrict__ nmskey,
    unsigned* __restrict__ hist)
{
  const int i = blockIdx.x*256 + threadIdx.x;
  if (i >= NANCH) return;
  const double a0=(double)amap[4*i+0], a1=(double)amap[4*i+1];
  const double a2=(double)amap[4*i+2], a3=(double)amap[4*i+3];
  const double d0=regd[4*i+0], d1=regd[4*i+1], d2=regd[4*i+2], d3=regd[4*i+3];
  const double ah = a2 - a0, aw = a3 - a1;
  const double cy = a0 + 0.5*ah + d0*ah;
  const double cx = a1 + 0.5*aw + d1*aw;
  const double h = ah * exp(d2), w = aw * exp(d3);
  double y1 = cy - 0.5*h, x1 = cx - 0.5*w, y2 = cy + 0.5*h, x2 = cx + 0.5*w;
  y1 = fmax(y1, 0.0); x1 = fmax(x1, 0.0);
  y2 = fmin(y2, 1600.0); x2 = fmin(x2, 2560.0);
  boxesd[4*i+0]=y1; boxesd[4*i+1]=x1; boxesd[4*i+2]=y2; boxesd[4*i+3]=x2;
  const double obj = scored[i];
  const bool ok = (y2 - y1 >= 16.0) && (x2 - x1 >= 16.0);
  const unsigned k32 = fkey((float)obj);
  key32[i] = k32;
  nmskey[i] = ok ? dkey(obj) : dkey(-1e9);
  atomicAdd(&hist[k32 >> 16], 1u);
}

// ---------------- top-6000 radix select on f32-rounded keys ----------------
__global__ __launch_bounds__(1024) void scan_hi(const unsigned* __restrict__ hist, int* __restrict__ meta){
  __shared__ unsigned part[1024];
  const int t = threadIdx.x;
  unsigned s = 0;
  for (int j = 0; j < 64; ++j) s += hist[65535 - (t*64 + j)];
  part[t] = s;
  __syncthreads();
  for (int off = 1; off < 1024; off <<= 1){
    unsigned v = (t >= off) ? part[t - off] : 0u;
    __syncthreads();
    part[t] += v;
    __syncthreads();
  }
  const unsigned incl = part[t], excl = incl - s;
  if (excl < PRE_NMS && incl >= PRE_NMS){
    unsigned cum = excl;
    for (int j = 0; j < 64; ++j){
      const int bin = 65535 - (t*64 + j);
      const unsigned c = hist[bin];
      if (cum + c >= PRE_NMS){ meta[0] = bin; meta[1] = (int)cum; break; }
      cum += c;
    }
  }
}

__global__ __launch_bounds__(256) void hist_lo(const unsigned* __restrict__ key,
                                               const int* __restrict__ meta, unsigned* __restrict__ hist){
  const int i = blockIdx.x*256 + threadIdx.x;
  if (i < NANCH){
    const unsigned k = key[i];
    if ((int)(k >> 16) == meta[0]) atomicAdd(&hist[k & 0xFFFFu], 1u);
  }
}

__global__ __launch_bounds__(1024) void scan_lo(const unsigned* __restrict__ hist, int* __restrict__ meta){
  __shared__ unsigned part[1024];
  const int t = threadIdx.x;
  const unsigned G0 = (unsigned)meta[1];
  unsigned s = 0;
  for (int j = 0; j < 64; ++j) s += hist[65535 - (t*64 + j)];
  part[t] = s;
  __syncthreads();
  for (int off = 1; off < 1024; off <<= 1){
    unsigned v = (t >= off) ? part[t - off] : 0u;
    __syncthreads();
    part[t] += v;
    __syncthreads();
  }
  const unsigned incl = G0 + part[t], excl = incl - s;
  if (excl < PRE_NMS && incl >= PRE_NMS){
    unsigned cum = excl;
    for (int j = 0; j < 64; ++j){
      const int bin = 65535 - (t*64 + j);
      const unsigned c = hist[bin];
      if (cum + c >= PRE_NMS){
        meta[2] = (int)(((unsigned)meta[0] << 16) | (unsigned)bin);
        meta[3] = (int)cum;
        meta[4] = PRE_NMS - (int)cum;
        break;
      }
      cum += c;
    }
  }
}

__global__ __launch_bounds__(256) void compact_k(
    const unsigned* __restrict__ key, const unsigned long long* __restrict__ nmskey,
    const double* __restrict__ boxesd, const int* __restrict__ meta,
    int* __restrict__ cnt, double* __restrict__ selboxd,
    unsigned long long* __restrict__ selkey, int* __restrict__ eqidx)
{
  const int i = blockIdx.x*256 + threadIdx.x;
  if (i >= NANCH) return;
  const unsigned k = key[i];
  const unsigned T = (unsigned)meta[2];
  if (k > T){
    const int s = atomicAdd(&cnt[0], 1);
    selboxd[4*s+0]=boxesd[4*i+0]; selboxd[4*s+1]=boxesd[4*i+1];
    selboxd[4*s+2]=boxesd[4*i+2]; selboxd[4*s+3]=boxesd[4*i+3];
    selkey[s] = nmskey[i];
  } else if (k == T){
    const int e = atomicAdd(&cnt[1], 1);
    if (e < EQCAP) eqidx[e] = i;
  }
}

__global__ __launch_bounds__(256) void rankeq(
    const double* __restrict__ scored, const double* __restrict__ boxesd,
    const unsigned long long* __restrict__ nmskey,
    const int* __restrict__ meta, const int* __restrict__ cnt,
    const int* __restrict__ eqidx, double* __restrict__ selboxd,
    unsigned long long* __restrict__ selkey)
{
  __shared__ int eq[EQCAP];
  const int t = threadIdx.x;
  int E = cnt[1]; if (E > EQCAP) E = EQCAP;
  const int R = meta[4], G2 = meta[3];
  for (int j = t; j < E; j += 256) eq[j] = eqidx[j];
  __syncthreads();
  for (int j = t; j < E; j += 256){
    const int my = eq[j];
    const double smy = scored[my];
    int rank = 0;
    for (int k2 = 0; k2 < E; ++k2){
      const int ok = eq[k2];
      const double sk = scored[ok];
      rank += ((sk > smy) || (sk == smy && ok < my)) ? 1 : 0;
    }
    if (rank < R){
      const int s = G2 + rank;
      selboxd[4*s+0]=boxesd[4*my+0]; selboxd[4*s+1]=boxesd[4*my+1];
      selboxd[4*s+2]=boxesd[4*my+2]; selboxd[4*s+3]=boxesd[4*my+3];
      selkey[s] = nmskey[my];
    }
  }
}

// ---------------- rank-by-counting scatter ----------------
__global__ __launch_bounds__(256) void rank_scatter(
    const unsigned long long* __restrict__ selkey, const double* __restrict__ selboxd,
    unsigned long long* __restrict__ skeys, double* __restrict__ sboxd)
{
  __shared__ unsigned long long k[PRE_NMS];
  const int t = threadIdx.x;
  for (int j = t; j < PRE_NMS; j += 256) k[j] = selkey[j];
  __syncthreads();
  const int j = blockIdx.x*256 + t;
  if (j >= PRE_NMS) return;
  const unsigned long long kj = k[j];
  int r = 0;
  for (int i = 0; i < PRE_NMS; i += 4){
    r += (int)((k[i+0] > kj) || (k[i+0] == kj && (i+0) < j));
    r += (int)((k[i+1] > kj) || (k[i+1] == kj && (i+1) < j));
    r += (int)((k[i+2] > kj) || (k[i+2] == kj && (i+2) < j));
    r += (int)((k[i+3] > kj) || (k[i+3] == kj && (i+3) < j));
  }
  skeys[r] = kj;
  sboxd[(size_t)r*4+0] = selboxd[(size_t)j*4+0];
  sboxd[(size_t)r*4+1] = selboxd[(size_t)j*4+1];
  sboxd[(size_t)r*4+2] = selboxd[(size_t)j*4+2];
  sboxd[(size_t)r*4+3] = selboxd[(size_t)j*4+3];
}

// ---------------- 6000x6000 IOU suppression bitmap ----------------
__global__ __launch_bounds__(256) void iou_bitmap(
    const double* __restrict__ sboxd, unsigned long long* __restrict__ rowbits)
{
  __shared__ double cbx[4096];           // 1024 col boxes
  const int g = blockIdx.y;              // 0..5 word-groups
  const int r0 = blockIdx.x * 16;
  const int t = threadIdx.x;
  const int cbase = g * 1024;
  for (int e = t; e < 4096; e += 256){
    const int bi = cbase + (e >> 2);
    cbx[e] = (bi < PRE_NMS) ? sboxd[(size_t)bi*4 + (e & 3)] : 0.0;
  }
  __syncthreads();
  const int r = r0 + (t >> 4);
  const int w = t & 15;
  const double by1 = sboxd[(size_t)r*4+0], bx1 = sboxd[(size_t)r*4+1];
  const double by2 = sboxd[(size_t)r*4+2], bx2 = sboxd[(size_t)r*4+3];
  const double a1 = fmax(by2-by1, 0.0) * fmax(bx2-bx1, 0.0);
  unsigned long long bits = 0ull;
  for (int b = 0; b < 64; ++b){
    const int bcol = (b + w) & 63;
    const int j = cbase + w*64 + bcol;
    if (j < PRE_NMS){
      const int ce = (w*64 + bcol)*4;
      const double c0 = cbx[ce+0], c1 = cbx[ce+1], c2 = cbx[ce+2], c3 = cbx[ce+3];
      const double yy1 = fmax(by1, c0), xx1 = fmax(bx1, c1);
      const double yy2 = fmin(by2, c2), xx2 = fmin(bx2, c3);
      const double inter = fmax(yy2-yy1, 0.0) * fmax(xx2-xx1, 0.0);
      const double a2 = fmax(c2-c0, 0.0) * fmax(c3-c1, 0.0);
      const double iou = inter / (a1 + a2 - inter + 1e-8);
      if (iou > 0.7) bits |= (1ull << bcol);
    }
  }
  rowbits[(size_t)r*128 + g*16 + w] = bits;
}

// ---------------- greedy scan: word-skipping (ctz) over suppression bitmap ----------------
__global__ __launch_bounds__(64) void greedy(
    const unsigned long long* __restrict__ skeys, const double* __restrict__ sboxd,
    const unsigned long long* __restrict__ rowbits, float* __restrict__ outp)
{
  const int t = threadIdx.x;
  const unsigned long long KEYTH = dkey(-5.0e8);
  int bad = PRE_NMS;
  for (int j = t; j < PRE_NMS; j += 64){
    if (skeys[j] <= KEYTH){ bad = j; break; }
  }
  #pragma unroll
  for (int off = 32; off > 0; off >>= 1){
    const int o = __shfl_down(bad, off, 64);
    bad = (o < bad) ? o : bad;
  }
  const int ilim = __builtin_amdgcn_readfirstlane(bad);

  // pre-suppress indices >= ilim
  auto maskfrom = [](int start) -> unsigned long long {
    if (start <= 0) return ~0ull;
    if (start >= 64) return 0ull;
    return (~0ull) << start;
  };
  unsigned long long s0 = maskfrom(ilim - t*64);
  unsigned long long s1 = (t < 30) ? maskfrom(ilim - (64 + t)*64) : ~0ull;

  int emitted = 0;
  for (int w = 0; w < 94 && emitted < POST_NMS; ++w){
    const unsigned long long sw = (w < 64) ? shfl_u64(s0, w) : shfl_u64(s1, w - 64);
    unsigned long long avail = ~sw;          // uniform across lanes
    while (avail && emitted < POST_NMS){
      const int b = __ffsll((long long)avail) - 1;
      const int i = w*64 + b;
      if (t < 4) outp[4*emitted + t] = (float)sboxd[(size_t)i*4 + t];
      const unsigned long long r0 = rowbits[(size_t)i*128 + t];
      const unsigned long long r1 = (t < 30) ? rowbits[(size_t)i*128 + 64 + t] : 0ull;
      s0 |= r0; s1 |= r1;
      ++emitted;
      const unsigned long long rw = (w < 64) ? shfl_u64(r0, w) : shfl_u64(r1, w - 64);
      avail &= ~rw;
      avail &= ~(1ull << b);
    }
  }
  for (int r = emitted; r < POST_NMS; ++r)
    if (t < 4) outp[4*r + t] = 0.f;
}

extern "C" void kernel_launch(void* const* d_in, const int* in_sizes, int n_in,
                              void* d_out, int out_size, void* d_ws, size_t ws_size,
                              hipStream_t stream)
{
  const float* fm   = (const float*)d_in[1];
  const float* amap = (const float*)d_in[2];
  const float* W1   = (const float*)d_in[4];
  const float* b1   = (const float*)d_in[5];
  const float* Wc   = (const float*)d_in[6];
  const float* bc   = (const float*)d_in[7];
  const float* Wr   = (const float*)d_in[8];
  const float* br   = (const float*)d_in[9];
  float* out = (float*)d_out;

  char* base = (char*)d_ws;
  size_t off = 0;
  auto A = [&](size_t n) -> char* {
    char* p = base + off;
    off = (off + n + 255) & ~(size_t)255;
    return p;
  };
  double* yd      = (double*)A(65536000);
  double* WT      = (double*)A(196608);
  double* scored  = (double*)A(1152000);
  double* regd    = (double*)A(4608000);
  unsigned* histc = (unsigned*)A(524328);        // hist1|hist2|cnt|meta contiguous
  double* boxesd              = (double*)A(4608000);
  unsigned long long* nmskey  = (unsigned long long*)A(1152000);
  unsigned* key32             = (unsigned*)A(576000);
  double* selboxd             = (double*)A(192000);
  unsigned long long* selkey  = (unsigned long long*)A(48000);
  unsigned long long* skeys   = (unsigned long long*)A(48000);
  double* sboxd               = (double*)A(192000);
  unsigned long long* rowbits = (unsigned long long*)A(6144000);
  int* eqidx                  = (int*)A(32768);

  unsigned* hist1 = histc;
  unsigned* hist2 = histc + 65536;
  int* cnt        = (int*)(histc + 131072);
  int* meta       = cnt + 2;

  hipMemsetAsync(histc, 0, (size_t)524328, stream);

  hipLaunchKernelGGL(prep_all, dim3(96), dim3(256), 0, stream, Wc, Wr, WT);
  hipLaunchKernelGGL(conv_gemm, dim3(500), dim3(256), 0, stream, fm, W1, b1, yd);
  hipLaunchKernelGGL(head2, dim3(1000), dim3(64), 0, stream, yd, WT, bc, br, out, scored, regd);
  hipLaunchKernelGGL(decode_hist, dim3((NANCH + 255)/256), dim3(256), 0, stream,
                     amap, scored, regd, boxesd, key32, nmskey, hist1);
  hipLaunchKernelGGL(scan_hi, dim3(1), dim3(1024), 0, stream, hist1, meta);
  hipLaunchKernelGGL(hist_lo, dim3((NANCH + 255)/256), dim3(256), 0, stream, key32, meta, hist2);
  hipLaunchKernelGGL(scan_lo, dim3(1), dim3(1024), 0, stream, hist2, meta);
  hipLaunchKernelGGL(compact_k, dim3((NANCH + 255)/256), dim3(256), 0, stream,
                     key32, nmskey, boxesd, meta, cnt, selboxd, selkey, eqidx);
  hipLaunchKernelGGL(rankeq, dim3(1), dim3(256), 0, stream,
                     scored, boxesd, nmskey, meta, cnt, eqidx, selboxd, selkey);
  hipLaunchKernelGGL(rank_scatter, dim3((PRE_NMS + 255)/256), dim3(256), 0, stream,
                     selkey, selboxd, skeys, sboxd);
  hipLaunchKernelGGL(iou_bitmap, dim3(375, 6), dim3(256), 0, stream, sboxd, rowbits);
  hipLaunchKernelGGL(greedy, dim3(1), dim3(64), 0, stream, skeys, sboxd, rowbits, out + 720000);
}